// Round 17
// baseline (328.047 us; speedup 1.0000x reference)
//
#include <hip/hip_runtime.h>
#include <hip/hip_bf16.h>
#include <math.h>

constexpr int N_NODES = 150000;
constexpr int N_EDGES = 1200000;
constexpr int NPGC    = 30;
constexpr int NGRAPH  = N_NODES / NPGC;
constexpr int RB_CS   = 256;
constexpr int RB_GAT  = 1024;
constexpr int NBKT    = (N_NODES + 255) / 256;
constexpr int ABLK    = 256;
constexpr int EPB     = (N_EDGES + ABLK - 1) / ABLK;

typedef unsigned int u32;
typedef unsigned short u16;
typedef unsigned char u8;
typedef __attribute__((ext_vector_type(4))) float f32x4;
typedef __attribute__((ext_vector_type(2))) float f32x2;

__device__ __forceinline__ float lrelu(float v) { return v > 0.f ? v : 0.2f * v; }
__device__ __forceinline__ void unpack8f8(uint2 v, float* f) {
  f32x2 p0 = __builtin_amdgcn_cvt_pk_f32_fp8((int)v.x, false);
  f32x2 p1 = __builtin_amdgcn_cvt_pk_f32_fp8((int)v.x, true);
  f32x2 p2 = __builtin_amdgcn_cvt_pk_f32_fp8((int)v.y, false);
  f32x2 p3 = __builtin_amdgcn_cvt_pk_f32_fp8((int)v.y, true);
  f[0] = p0.x; f[1] = p0.y; f[2] = p1.x; f[3] = p1.y;
  f[4] = p2.x; f[5] = p2.y; f[6] = p3.x; f[7] = p3.y;
}
__device__ __forceinline__ u32 pk4_fp8(float a, float b, float c, float d) {
  int lo = __builtin_amdgcn_cvt_pk_fp8_f32(a, b, 0, false);
  return (u32)__builtin_amdgcn_cvt_pk_fp8_f32(c, d, lo, true);
}
__device__ __forceinline__ long pk8_fp8(const float* f) {
  union { uint2 u; long l; } cv;
  cv.u.x = pk4_fp8(f[0], f[1], f[2], f[3]);
  cv.u.y = pk4_fp8(f[4], f[5], f[6], f[7]);
  return cv.l;
}
__device__ __forceinline__ void decode_e(u32 ent, int& r, float& w) {
  r = (int)(ent >> 14);
  w = (float)(ent & 16383u) * (1.0f / 16384.0f);
}

// ---------------- CSR build: binned two-pass partition ----------------

__global__ __launch_bounds__(256) void k_a1(const int* __restrict__ col,
                                            int* __restrict__ histG, int ne) {
  __shared__ int hist[NBKT];
  int blk = blockIdx.x, tid = threadIdx.x;
  for (int i = tid; i < NBKT; i += 256) hist[i] = 0;
  __syncthreads();
  int s = blk * EPB;
  int e = s + EPB; if (e > ne) e = ne;
  for (int p = s + tid; p < e; p += 256) atomicAdd(&hist[col[p] >> 8], 1);
  __syncthreads();
  for (int i = tid; i < NBKT; i += 256) histG[i * ABLK + blk] = hist[i];
}

__global__ __launch_bounds__(256) void k_s1(int* __restrict__ histG,
                                            int* __restrict__ btot) {
  __shared__ int ts[256];
  int b = blockIdx.x, tid = threadIdx.x;
  int v = histG[b * ABLK + tid];
  ts[tid] = v;
  __syncthreads();
  for (int off = 1; off < 256; off <<= 1) {
    int t = (tid >= off) ? ts[tid - off] : 0;
    __syncthreads();
    ts[tid] += t;
    __syncthreads();
  }
  histG[b * ABLK + tid] = ts[tid] - v;
  if (tid == 255) btot[b] = ts[255];
}

__global__ __launch_bounds__(256) void k_s2(const int* __restrict__ btot,
                                            int* __restrict__ ebase) {
  __shared__ int ts[256];
  int tid = threadIdx.x;
  int v[3]; int s = 0;
  #pragma unroll
  for (int k = 0; k < 3; ++k) {
    int idx = tid * 3 + k;
    v[k] = (idx < NBKT) ? btot[idx] : 0;
    s += v[k];
  }
  ts[tid] = s;
  __syncthreads();
  for (int off = 1; off < 256; off <<= 1) {
    int t = (tid >= off) ? ts[tid - off] : 0;
    __syncthreads();
    ts[tid] += t;
    __syncthreads();
  }
  int run = ts[tid] - s;
  #pragma unroll
  for (int k = 0; k < 3; ++k) {
    int idx = tid * 3 + k;
    if (idx < NBKT) ebase[idx] = run;
    run += v[k];
  }
  if (tid == 255) ebase[NBKT] = ts[255];
}

__global__ __launch_bounds__(256) void k_a2(const int* __restrict__ row,
                                            const int* __restrict__ col,
                                            const float* __restrict__ ew,
                                            const int* __restrict__ histG,
                                            const int* __restrict__ ebase,
                                            uint2* __restrict__ tmp, int ne) {
  __shared__ int scur[NBKT];
  int blk = blockIdx.x, tid = threadIdx.x;
  for (int i = tid; i < NBKT; i += 256) scur[i] = ebase[i] + histG[i * ABLK + blk];
  __syncthreads();
  int s = blk * EPB;
  int e = s + EPB; if (e > ne) e = ne;
  for (int p = s + tid; p < e; p += 256) {
    int c = col[p];
    float w = ew[p];
    u32 wq = (u32)(w * 16384.0f + 0.5f);
    if (wq > 16383u) wq = 16383u;
    u32 ent = ((u32)row[p] << 14) | wq;
    int pos = atomicAdd(&scur[c >> 8], 1);
    uint2 v; v.x = (u32)c; v.y = ent;
    tmp[pos] = v;
  }
}

__global__ __launch_bounds__(256) void k_b(const uint2* __restrict__ tmp,
                                           const int* __restrict__ ebase,
                                           int* __restrict__ rend,
                                           u32* __restrict__ csr_e, int n) {
  __shared__ int cnt[256], cur[256], ts[256];
  int b = blockIdx.x, tid = threadIdx.x;
  int s = ebase[b], e = ebase[b + 1];
  cnt[tid] = 0;
  __syncthreads();
  for (int p = s + tid; p < e; p += 256)
    atomicAdd(&cnt[(int)tmp[p].x & 255], 1);
  __syncthreads();
  int v = cnt[tid];
  ts[tid] = v;
  __syncthreads();
  for (int off = 1; off < 256; off <<= 1) {
    int t = (tid >= off) ? ts[tid - off] : 0;
    __syncthreads();
    ts[tid] += t;
    __syncthreads();
  }
  int node = (b << 8) + tid;
  if (node < n) rend[node] = s + ts[tid];
  cur[tid] = s + ts[tid] - v;
  __syncthreads();
  for (int p = s + tid; p < e; p += 256) {
    uint2 t2 = tmp[p];
    int pos = atomicAdd(&cur[(int)t2.x & 255], 1);
    csr_e[pos] = t2.y;
  }
}

// ---------------- normalization ----------------

__global__ __launch_bounds__(256) void k_cs1(const float* __restrict__ x,
                                             float* __restrict__ pb, int n) {
  __shared__ float ls[4][6];
  float s0 = 0, s1 = 0, s2 = 0;
  float m0 = -INFINITY, m1 = -INFINITY, m2 = -INFINITY;
  for (int i = blockIdx.x * 256 + threadIdx.x; i < n; i += RB_CS * 256) {
    float v0 = x[3 * i], v1 = x[3 * i + 1], v2 = x[3 * i + 2];
    s0 += v0; s1 += v1; s2 += v2;
    m0 = fmaxf(m0, v0); m1 = fmaxf(m1, v1); m2 = fmaxf(m2, v2);
  }
  for (int o = 32; o > 0; o >>= 1) {
    s0 += __shfl_down(s0, o); s1 += __shfl_down(s1, o); s2 += __shfl_down(s2, o);
    m0 = fmaxf(m0, __shfl_down(m0, o));
    m1 = fmaxf(m1, __shfl_down(m1, o));
    m2 = fmaxf(m2, __shfl_down(m2, o));
  }
  int w = threadIdx.x >> 6;
  if ((threadIdx.x & 63) == 0) {
    ls[w][0] = s0; ls[w][1] = s1; ls[w][2] = s2;
    ls[w][3] = m0; ls[w][4] = m1; ls[w][5] = m2;
  }
  __syncthreads();
  if (threadIdx.x == 0) {
    float* o = pb + blockIdx.x * 8;
    o[0] = ls[0][0] + ls[1][0] + ls[2][0] + ls[3][0];
    o[1] = ls[0][1] + ls[1][1] + ls[2][1] + ls[3][1];
    o[2] = ls[0][2] + ls[1][2] + ls[2][2] + ls[3][2];
    o[3] = fmaxf(fmaxf(ls[0][3], ls[1][3]), fmaxf(ls[2][3], ls[3][3]));
    o[4] = fmaxf(fmaxf(ls[0][4], ls[1][4]), fmaxf(ls[2][4], ls[3][4]));
    o[5] = fmaxf(fmaxf(ls[0][5], ls[1][5]), fmaxf(ls[2][5], ls[3][5]));
  }
}

__global__ __launch_bounds__(256) void k_norm(const float* __restrict__ x,
                                              const float* __restrict__ pcs,
                                              float4* __restrict__ x0v, int n) {
  __shared__ float ls[4][6];
  __shared__ float rs[6];
  int tid = threadIdx.x;
  const float* p = pcs + tid * 8;
  float s0 = p[0], s1 = p[1], s2 = p[2], m0 = p[3], m1 = p[4], m2 = p[5];
  for (int o = 32; o > 0; o >>= 1) {
    s0 += __shfl_down(s0, o); s1 += __shfl_down(s1, o); s2 += __shfl_down(s2, o);
    m0 = fmaxf(m0, __shfl_down(m0, o));
    m1 = fmaxf(m1, __shfl_down(m1, o));
    m2 = fmaxf(m2, __shfl_down(m2, o));
  }
  int w = tid >> 6;
  if ((tid & 63) == 0) {
    ls[w][0] = s0; ls[w][1] = s1; ls[w][2] = s2;
    ls[w][3] = m0; ls[w][4] = m1; ls[w][5] = m2;
  }
  __syncthreads();
  if (tid == 0) {
    float inv_n = 1.0f / (float)N_NODES;
    #pragma unroll
    for (int c = 0; c < 3; ++c) {
      float mean = (ls[0][c] + ls[1][c] + ls[2][c] + ls[3][c]) * inv_n;
      float mx = fmaxf(fmaxf(ls[0][3 + c], ls[1][3 + c]), fmaxf(ls[2][3 + c], ls[3][3 + c]));
      rs[c] = mean;
      rs[3 + c] = 1.0f / (mx - mean);
    }
  }
  __syncthreads();
  int node = blockIdx.x * 256 + tid;
  if (node < n) {
    float vx = x[3 * node], vy = x[3 * node + 1], vz = x[3 * node + 2];
    float4 o;
    o.x = (vx - rs[0]) * rs[3];
    o.y = (vy - rs[1]) * rs[4];
    o.z = (vz - rs[2]) * rs[5];
    o.w = 0.f;
    x0v[node] = o;
  }
}

// ---------------- layer 1 ----------------

__global__ __launch_bounds__(256) void k_gather3(
    const float4* __restrict__ x0v, const int* __restrict__ rend,
    const u32* __restrict__ csr_e, const float* __restrict__ epsp,
    float* __restrict__ agg1, int n) {
  int wv = (blockIdx.x * 256 + threadIdx.x) >> 6;
  int lane = threadIdx.x & 63;
  int sub = lane >> 4, sl = lane & 15;
  int node = wv * 4 + sub;
  if (node >= n) return;
  int s = (node == 0) ? 0 : rend[node - 1];
  int e = rend[node];
  float a0 = 0, a1 = 0, a2 = 0, b0 = 0, b1 = 0, b2 = 0;
  for (int p = s + sl; p < e; p += 16) {
    int r; float w;
    decode_e(csr_e[p], r, w);
    float4 v = x0v[r];
    a0 += v.x * w; a1 += v.y * w; a2 += v.z * w;
    b0 += v.x; b1 += v.y; b2 += v.z;
  }
  #pragma unroll
  for (int o = 1; o < 16; o <<= 1) {
    a0 += __shfl_xor(a0, o); a1 += __shfl_xor(a1, o); a2 += __shfl_xor(a2, o);
    b0 += __shfl_xor(b0, o); b1 += __shfl_xor(b1, o); b2 += __shfl_xor(b2, o);
  }
  if (sl == 0) {
    float eps1 = 1.0f + epsp[0];
    float4 hv = x0v[node];
    float4* ap = (float4*)(agg1 + (size_t)node * 8);
    float4 A; A.x = a0; A.y = a1; A.z = a2; A.w = 0.f;
    float4 M; M.x = eps1 * hv.x + b0; M.y = eps1 * hv.y + b1; M.z = eps1 * hv.z + b2; M.w = 0.f;
    ap[0] = A; ap[1] = M;
  }
}

__global__ __launch_bounds__(256) void k_node1(
    const float* __restrict__ agg1, u8* __restrict__ h1,
    const float* __restrict__ gw, const float* __restrict__ gb,
    const float* __restrict__ w1, const float* __restrict__ b1,
    const float* __restrict__ w2, const float* __restrict__ b2, int n) {
  __shared__ float Ws[96], W1s[30], W2s[320], GBs[32], B1s[10], B2s[32];
  int tid = threadIdx.x;
  if (tid < 96) Ws[tid] = gw[tid];
  if (tid < 30) W1s[tid] = w1[tid];
  for (int i = tid; i < 320; i += 256) W2s[i] = w2[i];
  if (tid < 32) { GBs[tid] = gb[tid]; B2s[tid] = b2[tid]; }
  if (tid < 10) B1s[tid] = b1[tid];
  __syncthreads();
  int nd = blockIdx.x * 256 + tid;
  if (nd >= n) return;
  const float* a = agg1 + (size_t)nd * 8;
  float a0 = a[0], a1 = a[1], a2 = a[2], m0 = a[4], m1 = a[5], m2 = a[6];
  float t[10];
  #pragma unroll
  for (int h = 0; h < 10; ++h)
    t[h] = fmaxf(B1s[h] + m0 * W1s[h] + m1 * W1s[10 + h] + m2 * W1s[20 + h], 0.f);
  float vout[64];
  #pragma unroll
  for (int j = 0; j < 32; ++j)
    vout[j] = lrelu(GBs[j] + a0 * Ws[j] + a1 * Ws[32 + j] + a2 * Ws[64 + j]);
  #pragma unroll
  for (int j = 0; j < 32; ++j) {
    float s = B2s[j];
    #pragma unroll
    for (int h = 0; h < 10; ++h) s += t[h] * W2s[h * 32 + j];
    vout[32 + j] = fmaxf(s, 0.f);
  }
  u32 f8_[16];
  #pragma unroll
  for (int q = 0; q < 16; ++q)
    f8_[q] = pk4_fp8(vout[4 * q], vout[4 * q + 1], vout[4 * q + 2], vout[4 * q + 3]);
  uint4* dst = (uint4*)(h1 + (size_t)nd * 64);
  #pragma unroll
  for (int q = 0; q < 4; ++q) {
    uint4 v; v.x = f8_[q * 4]; v.y = f8_[q * 4 + 1]; v.z = f8_[q * 4 + 2]; v.w = f8_[q * 4 + 3];
    dst[q] = v;
  }
}

// ---------------- fused layer: fp8 gather (LDS) + fp8 MFMA node update ----------------
// Per batch of NPB nodes: waves gather [AGG|M] fp8 rows into LDS AM (padded stride),
// barrier, then the block computes NTILE_B 16-node MFMA tiles reading fragments
// from LDS. Weights in registers. Output fp8 rows to global.

template <int FIN, int FOUT>
__global__ __launch_bounds__(256) void k_layerF(
    const u8* __restrict__ hp, u8* __restrict__ ho,
    const int* __restrict__ rend, const u32* __restrict__ csr_e,
    const float* __restrict__ epsp,
    const float* __restrict__ gw, const float* __restrict__ gb,
    const float* __restrict__ w1, const float* __restrict__ b1,
    const float* __restrict__ w2, const float* __restrict__ b2, int n) {
  constexpr int LPR = FIN / 8;        // lanes per gathered row
  constexpr int GPN = 64 / LPR;       // nodes per wave-gather
  constexpr int NPB = GPN * 4;        // nodes per block batch (32 / 16)
  constexpr int NTILE_B = NPB / 16;   // MFMA tiles per batch (2 / 1)
  constexpr int STP = 2 * FIN + 16;   // padded AM row stride (bytes); STP/4 mod 32 = 4
  constexpr int HST = 2 * FOUT;
  constexpr int NKS = FIN / 32;
  constexpr int NJT = FOUT / 16;
  constexpr int JPW = NJT / 4;
  constexpr int TPB = 40;
  __shared__ __align__(16) u8 AM[NPB][STP];
  __shared__ __align__(8)  u8 Tl[4][16][TPB];
  const int tid = threadIdx.x;
  const int w = tid >> 6, lane = tid & 63;
  const int grp = lane / LPR, fl = lane & (LPR - 1);
  const int c16 = lane & 15, kg = lane >> 4;
  for (int i = lane; i < 16 * TPB; i += 64) Tl[w][i / TPB][i % TPB] = 0;
  // preload fp8-packed weight fragments into registers
  long aWt[JPW][NKS], aW1[NKS], aW2[JPW];
  float gbv[JPW], b2v[JPW];
  float b1v = (c16 < 10) ? b1[c16] : 0.f;
  {
    float f[8];
    #pragma unroll
    for (int ks = 0; ks < NKS; ++ks) {
      #pragma unroll
      for (int i = 0; i < 8; ++i) {
        int kk = ks * 32 + kg * 8 + i;
        f[i] = (c16 < 10) ? w1[kk * 10 + c16] : 0.f;
      }
      aW1[ks] = pk8_fp8(f);
    }
    #pragma unroll
    for (int jj = 0; jj < JPW; ++jj) {
      int colj = (w * JPW + jj) * 16 + c16;
      gbv[jj] = gb[colj]; b2v[jj] = b2[colj];
      #pragma unroll
      for (int ks = 0; ks < NKS; ++ks) {
        #pragma unroll
        for (int i = 0; i < 8; ++i)
          f[i] = gw[(ks * 32 + kg * 8 + i) * FOUT + colj];
        aWt[jj][ks] = pk8_fp8(f);
      }
      #pragma unroll
      for (int i = 0; i < 8; ++i) {
        int kk = kg * 8 + i;
        f[i] = (kk < 10) ? w2[kk * FOUT + colj] : 0.f;
      }
      aW2[jj] = pk8_fp8(f);
    }
  }
  const float eps1 = 1.0f + epsp[0];
  const int nbatch = (n + NPB - 1) / NPB;
  for (int bt = blockIdx.x; bt < nbatch; bt += gridDim.x) {
    const int base = bt * NPB;
    // ---- gather phase (round-13 reduction-free loop, dest = LDS) ----
    {
      int node = base + w * GPN + grp;
      if (node < n) {
        int s = (node == 0) ? 0 : rend[node - 1];
        int e = rend[node];
        float aa[8] = {0, 0, 0, 0, 0, 0, 0, 0};
        float bb[8] = {0, 0, 0, 0, 0, 0, 0, 0};
        for (int p = s; p < e; ++p) {
          int r; float wt;
          decode_e(csr_e[p], r, wt);
          uint2 v = *(const uint2*)(hp + (size_t)r * FIN + fl * 8);
          float f[8]; unpack8f8(v, f);
          #pragma unroll
          for (int i = 0; i < 8; ++i) { aa[i] += f[i] * wt; bb[i] += f[i]; }
        }
        uint2 hv = *(const uint2*)(hp + (size_t)node * FIN + fl * 8);
        float hm[8]; unpack8f8(hv, hm);
        float m[8];
        #pragma unroll
        for (int i = 0; i < 8; ++i) m[i] = eps1 * hm[i] + bb[i];
        uint2 pa, pm;
        pa.x = pk4_fp8(aa[0], aa[1], aa[2], aa[3]);
        pa.y = pk4_fp8(aa[4], aa[5], aa[6], aa[7]);
        pm.x = pk4_fp8(m[0], m[1], m[2], m[3]);
        pm.y = pk4_fp8(m[4], m[5], m[6], m[7]);
        int nl = w * GPN + grp;
        *(uint2*)&AM[nl][fl * 8] = pa;
        *(uint2*)&AM[nl][FIN + fl * 8] = pm;
      }
    }
    __syncthreads();
    // ---- compute phase: per 16-node tile, identical to k_nodeM but LDS source ----
    #pragma unroll
    for (int tt = 0; tt < NTILE_B; ++tt) {
      const int nb = base + tt * 16;
      if (nb < n) {
        const u8* arow = &AM[tt * 16 + c16][0];
        long aA[NKS], aM[NKS];
        #pragma unroll
        for (int ks = 0; ks < NKS; ++ks) {
          aA[ks] = *(const long*)(arow + ks * 32 + kg * 8);
          aM[ks] = *(const long*)(arow + FIN + ks * 32 + kg * 8);
        }
        f32x4 tacc = {0.f, 0.f, 0.f, 0.f};
        #pragma unroll
        for (int ks = 0; ks < NKS; ++ks)
          tacc = __builtin_amdgcn_mfma_f32_16x16x32_fp8_fp8(aM[ks], aW1[ks], tacc, 0, 0, 0);
        #pragma unroll
        for (int r = 0; r < 4; ++r) {
          float tv = fmaxf(tacc[r] + b1v, 0.f);
          Tl[w][kg * 4 + r][c16] = (u8)pk4_fp8(tv, tv, tv, tv);
        }
        #pragma unroll
        for (int jj = 0; jj < JPW; ++jj) {
          f32x4 acc = {0.f, 0.f, 0.f, 0.f};
          #pragma unroll
          for (int ks = 0; ks < NKS; ++ks)
            acc = __builtin_amdgcn_mfma_f32_16x16x32_fp8_fp8(aA[ks], aWt[jj][ks], acc, 0, 0, 0);
          int colj = (w * JPW + jj) * 16 + c16;
          #pragma unroll
          for (int r = 0; r < 4; ++r) {
            int nd = nb + kg * 4 + r;
            float val = lrelu(acc[r] + gbv[jj]);
            ho[(size_t)nd * HST + colj] = (u8)pk4_fp8(val, val, val, val);
          }
        }
        long at = *(const long*)&Tl[w][c16][kg * 8];
        #pragma unroll
        for (int jj = 0; jj < JPW; ++jj) {
          f32x4 acc = {0.f, 0.f, 0.f, 0.f};
          acc = __builtin_amdgcn_mfma_f32_16x16x32_fp8_fp8(at, aW2[jj], acc, 0, 0, 0);
          int colj = (w * JPW + jj) * 16 + c16;
          #pragma unroll
          for (int r = 0; r < 4; ++r) {
            int nd = nb + kg * 4 + r;
            float val = fmaxf(acc[r] + b2v[jj], 0.f);
            ho[(size_t)nd * HST + FOUT + colj] = (u8)pk4_fp8(val, val, val, val);
          }
        }
      }
    }
    __syncthreads();  // protect AM before next batch's gather
  }
}

// ---------------- GAT + pool (h3 fp8) ----------------

__global__ __launch_bounds__(256) void k_hjb(const u8* __restrict__ h3,
                                             const float* __restrict__ gw,
                                             const float* __restrict__ att,
                                             float* __restrict__ hj,
                                             float* __restrict__ pem, int n) {
  __shared__ float gws[256];
  __shared__ float ls[4];
  int tid = threadIdx.x;
  gws[tid] = gw[tid];
  __syncthreads();
  int w = tid >> 6, lane = tid & 63;
  float a = att[0];
  float m = -INFINITY;
  for (int node = blockIdx.x * 4 + w; node < n; node += RB_GAT * 4) {
    u32 v = *(const u32*)(h3 + (size_t)node * 256 + lane * 4);
    f32x2 p0 = __builtin_amdgcn_cvt_pk_f32_fp8((int)v, false);
    f32x2 p1 = __builtin_amdgcn_cvt_pk_f32_fp8((int)v, true);
    float acc = p0.x * gws[lane * 4] + p0.y * gws[lane * 4 + 1] +
                p1.x * gws[lane * 4 + 2] + p1.y * gws[lane * 4 + 3];
    for (int o = 32; o > 0; o >>= 1) acc += __shfl_down(acc, o);
    if (lane == 0) {
      hj[node] = acc;
      m = fmaxf(m, lrelu(a * acc));
    }
  }
  if (lane == 0) ls[w] = m;
  __syncthreads();
  if (tid == 0) pem[blockIdx.x] = fmaxf(fmaxf(ls[0], ls[1]), fmaxf(ls[2], ls[3]));
}

__global__ __launch_bounds__(256) void k_gat(const int* __restrict__ rend,
                                             const u32* __restrict__ csr_e,
                                             const float* __restrict__ hj,
                                             const float* __restrict__ att,
                                             const float* __restrict__ pem,
                                             float* __restrict__ scat,
                                             float* __restrict__ pga, int n) {
  __shared__ float ls[4];
  __shared__ float msh;
  int tid = threadIdx.x;
  float m = fmaxf(fmaxf(pem[tid], pem[tid + 256]),
                  fmaxf(pem[tid + 512], pem[tid + 768]));
  for (int o = 32; o > 0; o >>= 1) m = fmaxf(m, __shfl_down(m, o));
  int w = tid >> 6;
  if ((tid & 63) == 0) ls[w] = m;
  __syncthreads();
  if (tid == 0) msh = fmaxf(fmaxf(ls[0], ls[1]), fmaxf(ls[2], ls[3]));
  __syncthreads();
  m = msh;
  float a = att[0];
  float lsum = 0.f;
  for (int c = blockIdx.x * 256 + tid; c < n; c += RB_GAT * 256) {
    int s = (c == 0) ? 0 : rend[c - 1];
    int e = rend[c];
    float acc = 0.f;
    for (int p = s; p < e; ++p) {
      float h = hj[(int)(csr_e[p] >> 14)];
      float pex = expf(lrelu(a * h) - m);
      lsum += pex;
      acc += pex * h;
    }
    scat[c] = acc;
  }
  __syncthreads();
  for (int o = 32; o > 0; o >>= 1) lsum += __shfl_down(lsum, o);
  if ((tid & 63) == 0) ls[w] = lsum;
  __syncthreads();
  if (tid == 0) pga[blockIdx.x] = ls[0] + ls[1] + ls[2] + ls[3];
}

__global__ __launch_bounds__(256) void k_pool(
    const u8* __restrict__ h3, const float* __restrict__ scat,
    const float* __restrict__ pga,
    const float* __restrict__ lw, const float* __restrict__ lb,
    const float* __restrict__ l2w, const float* __restrict__ l2b,
    float* __restrict__ out, int ng) {
  __shared__ float ls[4];
  __shared__ float pooled[256];
  __shared__ float aw[NPGC];
  __shared__ float y[10];
  int g = blockIdx.x;
  if (g >= ng) return;
  int tid = threadIdx.x;
  float s = pga[tid] + pga[tid + 256] + pga[tid + 512] + pga[tid + 768];
  for (int o = 32; o > 0; o >>= 1) s += __shfl_down(s, o);
  int w = tid >> 6;
  if ((tid & 63) == 0) ls[w] = s;
  __syncthreads();
  float inv_sexp = 1.0f / (ls[0] + ls[1] + ls[2] + ls[3]);
  if (tid < NPGC) aw[tid] = scat[g * NPGC + tid] * inv_sexp;
  __syncthreads();
  const u8* base = h3 + (size_t)g * NPGC * 256;
  float acc = 0.f;
  #pragma unroll
  for (int u = 0; u < NPGC; ++u) {
    f32x2 p = __builtin_amdgcn_cvt_pk_f32_fp8((int)(u32)base[u * 256 + tid], false);
    acc += p.x * aw[u];
  }
  pooled[tid] = acc * (1.0f / NPGC);
  __syncthreads();
  if (tid < 10) {
    float sy = lb[tid];
    for (int f = 0; f < 256; ++f) sy += pooled[f] * lw[f * 10 + tid];
    y[tid] = sy;
  }
  __syncthreads();
  if (tid == 0) {
    float sy = l2b[0];
    #pragma unroll
    for (int k = 0; k < 10; ++k) sy += y[k] * l2w[k];
    out[g] = 1.0f / (1.0f + expf(-sy));
  }
}

extern "C" void kernel_launch(void* const* d_in, const int* in_sizes, int n_in,
                              void* d_out, int out_size, void* d_ws, size_t ws_size,
                              hipStream_t stream) {
  const float* x        = (const float*)d_in[0];
  const int*   eidx     = (const int*)d_in[1];
  const float* ew       = (const float*)d_in[2];
  const float* gcn1_w   = (const float*)d_in[3];
  const float* gcn1_b   = (const float*)d_in[4];
  const float* gcn2_w   = (const float*)d_in[5];
  const float* gcn2_b   = (const float*)d_in[6];
  const float* gcn3_w   = (const float*)d_in[7];
  const float* gcn3_b   = (const float*)d_in[8];
  const float* gin1_w1  = (const float*)d_in[9];
  const float* gin1_b1  = (const float*)d_in[10];
  const float* gin1_w2  = (const float*)d_in[11];
  const float* gin1_b2  = (const float*)d_in[12];
  const float* gin1_eps = (const float*)d_in[13];
  const float* gin2_w1  = (const float*)d_in[14];
  const float* gin2_b1  = (const float*)d_in[15];
  const float* gin2_w2  = (const float*)d_in[16];
  const float* gin2_b2  = (const float*)d_in[17];
  const float* gin2_eps = (const float*)d_in[18];
  const float* gin3_w1  = (const float*)d_in[19];
  const float* gin3_b1  = (const float*)d_in[20];
  const float* gin3_w2  = (const float*)d_in[21];
  const float* gin3_b2  = (const float*)d_in[22];
  const float* gin3_eps = (const float*)d_in[23];
  const float* gat_w    = (const float*)d_in[24];
  const float* gat_att  = (const float*)d_in[25];
  const float* lin_w    = (const float*)d_in[26];
  const float* lin_b    = (const float*)d_in[27];
  const float* lin2_w   = (const float*)d_in[28];
  const float* lin2_b   = (const float*)d_in[29];
  float* out = (float*)d_out;

  const int* row = eidx;
  const int* col = eidx + N_EDGES;

  // Workspace (~198 MB). Fused layers require h_in / h_out in DISJOINT regions:
  //  R1 [N*512 B] @0:      tmp uint2[E] (N*64) -> {x0v N*16 | agg1 N*32 | h1 fp8 N*64}
  //                        -> {hj f32 N*4 @0 | scat f32 N*4 @N*4} (GAT phase; h1 dead)
  //  R2 [N*512 B] @N*512:  h2 fp8 N*128  (written by L2 fused, read by L3 fused)
  //  R3 [N*256 B] @N*1024: h3 fp8 N*256  (written by L3 fused; no overlap with h2)
  //  tail @N*1280: rend N*4 | csr_e N*32 | histG (padded 602112 B) | btot | ebase |
  //  pcs | pem | pga
  char* B = (char*)d_ws;
  uint2*  tmp   = (uint2*)B;
  float4* x0v   = (float4*)B;
  float*  agg1  = (float*)(B + (size_t)N_NODES * 16);
  u8*     h1    = (u8*)(B + (size_t)N_NODES * 48);
  float*  hj    = (float*)B;
  float*  scat  = (float*)(B + (size_t)N_NODES * 4);
  u8*     h2    = (u8*)(B + (size_t)N_NODES * 512);
  u8*     h3    = (u8*)(B + (size_t)N_NODES * 1024);
  int*    rend  = (int*)(B + (size_t)N_NODES * 1280);
  u32*    csr_e = (u32*)(B + (size_t)N_NODES * 1284);
  int*    histG = (int*)(B + (size_t)N_NODES * 1316);
  char*   TAIL  = B + (size_t)N_NODES * 1316 + 602112;
  int*    btot  = (int*)TAIL;
  int*    ebase = (int*)(TAIL + 4096);
  float*  pcs   = (float*)(TAIL + 8192);
  float*  pem   = (float*)(TAIL + 16384);
  float*  pga   = (float*)(TAIL + 20480);

  const int GN = (N_NODES + 255) / 256;

  // CSR build
  hipLaunchKernelGGL(k_a1, dim3(ABLK), dim3(256), 0, stream, col, histG, N_EDGES);
  hipLaunchKernelGGL(k_s1, dim3(NBKT), dim3(256), 0, stream, histG, btot);
  hipLaunchKernelGGL(k_s2, dim3(1), dim3(256), 0, stream, btot, ebase);
  hipLaunchKernelGGL(k_a2, dim3(ABLK), dim3(256), 0, stream,
                     row, col, ew, histG, ebase, tmp, N_EDGES);
  hipLaunchKernelGGL(k_b, dim3(NBKT), dim3(256), 0, stream, tmp, ebase, rend, csr_e, N_NODES);

  // normalization
  hipLaunchKernelGGL(k_cs1, dim3(RB_CS), dim3(256), 0, stream, x, pcs, N_NODES);
  hipLaunchKernelGGL(k_norm, dim3(GN), dim3(256), 0, stream, x, pcs, x0v, N_NODES);

  // layer 1: 3 -> 32|32 (h1 fp8)
  hipLaunchKernelGGL(k_gather3, dim3((N_NODES / 4 + 3) / 4), dim3(256), 0, stream,
                     x0v, rend, csr_e, gin1_eps, agg1, N_NODES);
  hipLaunchKernelGGL(k_node1, dim3(GN), dim3(256), 0, stream,
                     agg1, h1, gcn1_w, gcn1_b, gin1_w1, gin1_b1, gin1_w2, gin1_b2, N_NODES);

  // layer 2: 64 -> 64|64 (fused gather + MFMA; h1 -> h2)
  hipLaunchKernelGGL((k_layerF<64, 64>), dim3(2048), dim3(256), 0, stream,
                     h1, h2, rend, csr_e, gin2_eps,
                     gcn2_w, gcn2_b, gin2_w1, gin2_b1, gin2_w2, gin2_b2, N_NODES);

  // layer 3: 128 -> 128|128 (fused gather + MFMA; h2 -> h3, disjoint regions)
  hipLaunchKernelGGL((k_layerF<128, 128>), dim3(2048), dim3(256), 0, stream,
                     h2, h3, rend, csr_e, gin3_eps,
                     gcn3_w, gcn3_b, gin3_w1, gin3_b1, gin3_w2, gin3_b2, N_NODES);

  // GAT (h3 fp8)
  hipLaunchKernelGGL(k_hjb, dim3(RB_GAT), dim3(256), 0, stream, h3, gat_w, gat_att, hj, pem, N_NODES);
  hipLaunchKernelGGL(k_gat, dim3(RB_GAT), dim3(256), 0, stream,
                     rend, csr_e, hj, gat_att, pem, scat, pga, N_NODES);

  // pool + readout
  hipLaunchKernelGGL(k_pool, dim3(NGRAPH), dim3(256), 0, stream,
                     h3, scat, pga, lin_w, lin_b, lin2_w, lin2_b, out, NGRAPH);
}

// Round 18
// 272.436 us; speedup vs baseline: 1.2041x; 1.2041x over previous
//
#include <hip/hip_runtime.h>
#include <hip/hip_bf16.h>
#include <math.h>

constexpr int N_NODES = 150000;
constexpr int N_EDGES = 1200000;
constexpr int NPGC    = 30;
constexpr int NGRAPH  = N_NODES / NPGC;
constexpr int RB_CS   = 256;
constexpr int RB_GAT  = 1024;
constexpr int NBKT    = (N_NODES + 255) / 256;
constexpr int ABLK    = 256;
constexpr int EPB     = (N_EDGES + ABLK - 1) / ABLK;

typedef unsigned int u32;
typedef unsigned short u16;
typedef unsigned char u8;
typedef __attribute__((ext_vector_type(4))) float f32x4;
typedef __attribute__((ext_vector_type(2))) float f32x2;

__device__ __forceinline__ float lrelu(float v) { return v > 0.f ? v : 0.2f * v; }
__device__ __forceinline__ u16 f2bf(float f) {
  u32 u = __float_as_uint(f);
  return (u16)((u + 0x7FFFu + ((u >> 16) & 1u)) >> 16);
}
__device__ __forceinline__ void unpack8f8(uint2 v, float* f) {
  f32x2 p0 = __builtin_amdgcn_cvt_pk_f32_fp8((int)v.x, false);
  f32x2 p1 = __builtin_amdgcn_cvt_pk_f32_fp8((int)v.x, true);
  f32x2 p2 = __builtin_amdgcn_cvt_pk_f32_fp8((int)v.y, false);
  f32x2 p3 = __builtin_amdgcn_cvt_pk_f32_fp8((int)v.y, true);
  f[0] = p0.x; f[1] = p0.y; f[2] = p1.x; f[3] = p1.y;
  f[4] = p2.x; f[5] = p2.y; f[6] = p3.x; f[7] = p3.y;
}
__device__ __forceinline__ u32 pk4_fp8(float a, float b, float c, float d) {
  int lo = __builtin_amdgcn_cvt_pk_fp8_f32(a, b, 0, false);
  return (u32)__builtin_amdgcn_cvt_pk_fp8_f32(c, d, lo, true);
}
__device__ __forceinline__ long pk8_fp8(const float* f) {
  union { uint2 u; long l; } cv;
  cv.u.x = pk4_fp8(f[0], f[1], f[2], f[3]);
  cv.u.y = pk4_fp8(f[4], f[5], f[6], f[7]);
  return cv.l;
}
__device__ __forceinline__ void decode_e(u32 ent, int& r, float& w) {
  r = (int)(ent >> 14);
  w = (float)(ent & 16383u) * (1.0f / 16384.0f);
}

// ---------------- CSR build: binned two-pass partition ----------------

__global__ __launch_bounds__(256) void k_a1(const int* __restrict__ col,
                                            int* __restrict__ histG, int ne) {
  __shared__ int hist[NBKT];
  int blk = blockIdx.x, tid = threadIdx.x;
  for (int i = tid; i < NBKT; i += 256) hist[i] = 0;
  __syncthreads();
  int s = blk * EPB;
  int e = s + EPB; if (e > ne) e = ne;
  for (int p = s + tid; p < e; p += 256) atomicAdd(&hist[col[p] >> 8], 1);
  __syncthreads();
  for (int i = tid; i < NBKT; i += 256) histG[i * ABLK + blk] = hist[i];
}

__global__ __launch_bounds__(256) void k_s1(int* __restrict__ histG,
                                            int* __restrict__ btot) {
  __shared__ int ts[256];
  int b = blockIdx.x, tid = threadIdx.x;
  int v = histG[b * ABLK + tid];
  ts[tid] = v;
  __syncthreads();
  for (int off = 1; off < 256; off <<= 1) {
    int t = (tid >= off) ? ts[tid - off] : 0;
    __syncthreads();
    ts[tid] += t;
    __syncthreads();
  }
  histG[b * ABLK + tid] = ts[tid] - v;
  if (tid == 255) btot[b] = ts[255];
}

__global__ __launch_bounds__(256) void k_s2(const int* __restrict__ btot,
                                            int* __restrict__ ebase) {
  __shared__ int ts[256];
  int tid = threadIdx.x;
  int v[3]; int s = 0;
  #pragma unroll
  for (int k = 0; k < 3; ++k) {
    int idx = tid * 3 + k;
    v[k] = (idx < NBKT) ? btot[idx] : 0;
    s += v[k];
  }
  ts[tid] = s;
  __syncthreads();
  for (int off = 1; off < 256; off <<= 1) {
    int t = (tid >= off) ? ts[tid - off] : 0;
    __syncthreads();
    ts[tid] += t;
    __syncthreads();
  }
  int run = ts[tid] - s;
  #pragma unroll
  for (int k = 0; k < 3; ++k) {
    int idx = tid * 3 + k;
    if (idx < NBKT) ebase[idx] = run;
    run += v[k];
  }
  if (tid == 255) ebase[NBKT] = ts[255];
}

__global__ __launch_bounds__(256) void k_a2(const int* __restrict__ row,
                                            const int* __restrict__ col,
                                            const float* __restrict__ ew,
                                            const int* __restrict__ histG,
                                            const int* __restrict__ ebase,
                                            uint2* __restrict__ tmp, int ne) {
  __shared__ int scur[NBKT];
  int blk = blockIdx.x, tid = threadIdx.x;
  for (int i = tid; i < NBKT; i += 256) scur[i] = ebase[i] + histG[i * ABLK + blk];
  __syncthreads();
  int s = blk * EPB;
  int e = s + EPB; if (e > ne) e = ne;
  for (int p = s + tid; p < e; p += 256) {
    int c = col[p];
    float w = ew[p];
    u32 wq = (u32)(w * 16384.0f + 0.5f);
    if (wq > 16383u) wq = 16383u;
    u32 ent = ((u32)row[p] << 14) | wq;
    int pos = atomicAdd(&scur[c >> 8], 1);
    uint2 v; v.x = (u32)c; v.y = ent;
    tmp[pos] = v;
  }
}

__global__ __launch_bounds__(256) void k_b(const uint2* __restrict__ tmp,
                                           const int* __restrict__ ebase,
                                           int* __restrict__ rend,
                                           u32* __restrict__ csr_e, int n) {
  __shared__ int cnt[256], cur[256], ts[256];
  int b = blockIdx.x, tid = threadIdx.x;
  int s = ebase[b], e = ebase[b + 1];
  cnt[tid] = 0;
  __syncthreads();
  for (int p = s + tid; p < e; p += 256)
    atomicAdd(&cnt[(int)tmp[p].x & 255], 1);
  __syncthreads();
  int v = cnt[tid];
  ts[tid] = v;
  __syncthreads();
  for (int off = 1; off < 256; off <<= 1) {
    int t = (tid >= off) ? ts[tid - off] : 0;
    __syncthreads();
    ts[tid] += t;
    __syncthreads();
  }
  int node = (b << 8) + tid;
  if (node < n) rend[node] = s + ts[tid];
  cur[tid] = s + ts[tid] - v;
  __syncthreads();
  for (int p = s + tid; p < e; p += 256) {
    uint2 t2 = tmp[p];
    int pos = atomicAdd(&cur[(int)t2.x & 255], 1);
    csr_e[pos] = t2.y;
  }
}

// ---------------- normalization ----------------

__global__ __launch_bounds__(256) void k_cs1(const float* __restrict__ x,
                                             float* __restrict__ pb, int n) {
  __shared__ float ls[4][6];
  float s0 = 0, s1 = 0, s2 = 0;
  float m0 = -INFINITY, m1 = -INFINITY, m2 = -INFINITY;
  for (int i = blockIdx.x * 256 + threadIdx.x; i < n; i += RB_CS * 256) {
    float v0 = x[3 * i], v1 = x[3 * i + 1], v2 = x[3 * i + 2];
    s0 += v0; s1 += v1; s2 += v2;
    m0 = fmaxf(m0, v0); m1 = fmaxf(m1, v1); m2 = fmaxf(m2, v2);
  }
  for (int o = 32; o > 0; o >>= 1) {
    s0 += __shfl_down(s0, o); s1 += __shfl_down(s1, o); s2 += __shfl_down(s2, o);
    m0 = fmaxf(m0, __shfl_down(m0, o));
    m1 = fmaxf(m1, __shfl_down(m1, o));
    m2 = fmaxf(m2, __shfl_down(m2, o));
  }
  int w = threadIdx.x >> 6;
  if ((threadIdx.x & 63) == 0) {
    ls[w][0] = s0; ls[w][1] = s1; ls[w][2] = s2;
    ls[w][3] = m0; ls[w][4] = m1; ls[w][5] = m2;
  }
  __syncthreads();
  if (threadIdx.x == 0) {
    float* o = pb + blockIdx.x * 8;
    o[0] = ls[0][0] + ls[1][0] + ls[2][0] + ls[3][0];
    o[1] = ls[0][1] + ls[1][1] + ls[2][1] + ls[3][1];
    o[2] = ls[0][2] + ls[1][2] + ls[2][2] + ls[3][2];
    o[3] = fmaxf(fmaxf(ls[0][3], ls[1][3]), fmaxf(ls[2][3], ls[3][3]));
    o[4] = fmaxf(fmaxf(ls[0][4], ls[1][4]), fmaxf(ls[2][4], ls[3][4]));
    o[5] = fmaxf(fmaxf(ls[0][5], ls[1][5]), fmaxf(ls[2][5], ls[3][5]));
  }
}

__global__ __launch_bounds__(256) void k_norm(const float* __restrict__ x,
                                              const float* __restrict__ pcs,
                                              float4* __restrict__ x0v, int n) {
  __shared__ float ls[4][6];
  __shared__ float rs[6];
  int tid = threadIdx.x;
  const float* p = pcs + tid * 8;
  float s0 = p[0], s1 = p[1], s2 = p[2], m0 = p[3], m1 = p[4], m2 = p[5];
  for (int o = 32; o > 0; o >>= 1) {
    s0 += __shfl_down(s0, o); s1 += __shfl_down(s1, o); s2 += __shfl_down(s2, o);
    m0 = fmaxf(m0, __shfl_down(m0, o));
    m1 = fmaxf(m1, __shfl_down(m1, o));
    m2 = fmaxf(m2, __shfl_down(m2, o));
  }
  int w = tid >> 6;
  if ((tid & 63) == 0) {
    ls[w][0] = s0; ls[w][1] = s1; ls[w][2] = s2;
    ls[w][3] = m0; ls[w][4] = m1; ls[w][5] = m2;
  }
  __syncthreads();
  if (tid == 0) {
    float inv_n = 1.0f / (float)N_NODES;
    #pragma unroll
    for (int c = 0; c < 3; ++c) {
      float mean = (ls[0][c] + ls[1][c] + ls[2][c] + ls[3][c]) * inv_n;
      float mx = fmaxf(fmaxf(ls[0][3 + c], ls[1][3 + c]), fmaxf(ls[2][3 + c], ls[3][3 + c]));
      rs[c] = mean;
      rs[3 + c] = 1.0f / (mx - mean);
    }
  }
  __syncthreads();
  int node = blockIdx.x * 256 + tid;
  if (node < n) {
    float vx = x[3 * node], vy = x[3 * node + 1], vz = x[3 * node + 2];
    float4 o;
    o.x = (vx - rs[0]) * rs[3];
    o.y = (vy - rs[1]) * rs[4];
    o.z = (vz - rs[2]) * rs[5];
    o.w = 0.f;
    x0v[node] = o;
  }
}

// ---------------- layer 1 ----------------

__global__ __launch_bounds__(256) void k_gather3(
    const float4* __restrict__ x0v, const int* __restrict__ rend,
    const u32* __restrict__ csr_e, const float* __restrict__ epsp,
    float* __restrict__ agg1, int n) {
  int wv = (blockIdx.x * 256 + threadIdx.x) >> 6;
  int lane = threadIdx.x & 63;
  int sub = lane >> 4, sl = lane & 15;
  int node = wv * 4 + sub;
  if (node >= n) return;
  int s = (node == 0) ? 0 : rend[node - 1];
  int e = rend[node];
  float a0 = 0, a1 = 0, a2 = 0, b0 = 0, b1 = 0, b2 = 0;
  for (int p = s + sl; p < e; p += 16) {
    int r; float w;
    decode_e(csr_e[p], r, w);
    float4 v = x0v[r];
    a0 += v.x * w; a1 += v.y * w; a2 += v.z * w;
    b0 += v.x; b1 += v.y; b2 += v.z;
  }
  #pragma unroll
  for (int o = 1; o < 16; o <<= 1) {
    a0 += __shfl_xor(a0, o); a1 += __shfl_xor(a1, o); a2 += __shfl_xor(a2, o);
    b0 += __shfl_xor(b0, o); b1 += __shfl_xor(b1, o); b2 += __shfl_xor(b2, o);
  }
  if (sl == 0) {
    float eps1 = 1.0f + epsp[0];
    float4 hv = x0v[node];
    float4* ap = (float4*)(agg1 + (size_t)node * 8);
    float4 A; A.x = a0; A.y = a1; A.z = a2; A.w = 0.f;
    float4 M; M.x = eps1 * hv.x + b0; M.y = eps1 * hv.y + b1; M.z = eps1 * hv.z + b2; M.w = 0.f;
    ap[0] = A; ap[1] = M;
  }
}

__global__ __launch_bounds__(256) void k_node1(
    const float* __restrict__ agg1, u8* __restrict__ h1,
    const float* __restrict__ gw, const float* __restrict__ gb,
    const float* __restrict__ w1, const float* __restrict__ b1,
    const float* __restrict__ w2, const float* __restrict__ b2, int n) {
  __shared__ float Ws[96], W1s[30], W2s[320], GBs[32], B1s[10], B2s[32];
  int tid = threadIdx.x;
  if (tid < 96) Ws[tid] = gw[tid];
  if (tid < 30) W1s[tid] = w1[tid];
  for (int i = tid; i < 320; i += 256) W2s[i] = w2[i];
  if (tid < 32) { GBs[tid] = gb[tid]; B2s[tid] = b2[tid]; }
  if (tid < 10) B1s[tid] = b1[tid];
  __syncthreads();
  int nd = blockIdx.x * 256 + tid;
  if (nd >= n) return;
  const float* a = agg1 + (size_t)nd * 8;
  float a0 = a[0], a1 = a[1], a2 = a[2], m0 = a[4], m1 = a[5], m2 = a[6];
  float t[10];
  #pragma unroll
  for (int h = 0; h < 10; ++h)
    t[h] = fmaxf(B1s[h] + m0 * W1s[h] + m1 * W1s[10 + h] + m2 * W1s[20 + h], 0.f);
  float vout[64];
  #pragma unroll
  for (int j = 0; j < 32; ++j)
    vout[j] = lrelu(GBs[j] + a0 * Ws[j] + a1 * Ws[32 + j] + a2 * Ws[64 + j]);
  #pragma unroll
  for (int j = 0; j < 32; ++j) {
    float s = B2s[j];
    #pragma unroll
    for (int h = 0; h < 10; ++h) s += t[h] * W2s[h * 32 + j];
    vout[32 + j] = fmaxf(s, 0.f);
  }
  u32 f8_[16];
  #pragma unroll
  for (int q = 0; q < 16; ++q)
    f8_[q] = pk4_fp8(vout[4 * q], vout[4 * q + 1], vout[4 * q + 2], vout[4 * q + 3]);
  uint4* dst = (uint4*)(h1 + (size_t)nd * 64);
  #pragma unroll
  for (int q = 0; q < 4; ++q) {
    uint4 v; v.x = f8_[q * 4]; v.y = f8_[q * 4 + 1]; v.z = f8_[q * 4 + 2]; v.w = f8_[q * 4 + 3];
    dst[q] = v;
  }
}

// ---------------- fp8 SpMM: node-group per wave, 4-deep software-pipelined gather ----------------

template <int FIN>
__global__ __launch_bounds__(256) void k_spmmb(
    const u8* __restrict__ hp, u8* __restrict__ Aout,
    const int* __restrict__ rend, const u32* __restrict__ csr_e,
    const float* __restrict__ epsp, int n) {
  constexpr int LPR = FIN / 8;
  constexpr int GPN = 64 / LPR;
  int wv = (blockIdx.x * 256 + threadIdx.x) >> 6;
  int lane = threadIdx.x & 63;
  int grp = lane / LPR;
  int fl = lane & (LPR - 1);
  int node = wv * GPN + grp;
  if (node >= n) return;
  int s = (node == 0) ? 0 : rend[node - 1];
  int e = rend[node];
  float aa[8] = {0, 0, 0, 0, 0, 0, 0, 0};
  float bb[8] = {0, 0, 0, 0, 0, 0, 0, 0};
  int p = s;
  // 4-deep pipelined body: 4 independent row loads in flight per lane
  for (; p + 4 <= e; p += 4) {
    u32 e0 = csr_e[p], e1 = csr_e[p + 1], e2 = csr_e[p + 2], e3 = csr_e[p + 3];
    int r0, r1, r2, r3; float w0, w1, w2, w3;
    decode_e(e0, r0, w0); decode_e(e1, r1, w1);
    decode_e(e2, r2, w2); decode_e(e3, r3, w3);
    uint2 v0 = *(const uint2*)(hp + (size_t)r0 * FIN + fl * 8);
    uint2 v1 = *(const uint2*)(hp + (size_t)r1 * FIN + fl * 8);
    uint2 v2 = *(const uint2*)(hp + (size_t)r2 * FIN + fl * 8);
    uint2 v3 = *(const uint2*)(hp + (size_t)r3 * FIN + fl * 8);
    float f0[8], f1[8], f2[8], f3[8];
    unpack8f8(v0, f0); unpack8f8(v1, f1); unpack8f8(v2, f2); unpack8f8(v3, f3);
    #pragma unroll
    for (int i = 0; i < 8; ++i) {
      aa[i] += f0[i] * w0 + f1[i] * w1 + f2[i] * w2 + f3[i] * w3;
      bb[i] += f0[i] + f1[i] + f2[i] + f3[i];
    }
  }
  for (; p < e; ++p) {
    int r; float w;
    decode_e(csr_e[p], r, w);
    uint2 v = *(const uint2*)(hp + (size_t)r * FIN + fl * 8);
    float f[8]; unpack8f8(v, f);
    #pragma unroll
    for (int i = 0; i < 8; ++i) { aa[i] += f[i] * w; bb[i] += f[i]; }
  }
  float eps1 = 1.0f + epsp[0];
  uint2 hv = *(const uint2*)(hp + (size_t)node * FIN + fl * 8);
  float hm[8]; unpack8f8(hv, hm);
  float m[8];
  #pragma unroll
  for (int i = 0; i < 8; ++i) m[i] = eps1 * hm[i] + bb[i];
  uint2 pa, pm;
  pa.x = pk4_fp8(aa[0], aa[1], aa[2], aa[3]);
  pa.y = pk4_fp8(aa[4], aa[5], aa[6], aa[7]);
  pm.x = pk4_fp8(m[0], m[1], m[2], m[3]);
  pm.y = pk4_fp8(m[4], m[5], m[6], m[7]);
  *(uint2*)(Aout + (size_t)node * (2 * FIN) + fl * 8) = pa;
  *(uint2*)(Aout + (size_t)node * (2 * FIN) + FIN + fl * 8) = pm;
}

// ---------------- fp8 MFMA node update: register weights, barrier-free ----------------

template <int FIN, int FOUT, bool OUT8>
__global__ __launch_bounds__(256) void k_nodeM(
    const u8* __restrict__ Ain, void* __restrict__ ho_,
    const float* __restrict__ gw, const float* __restrict__ gb,
    const float* __restrict__ w1, const float* __restrict__ b1,
    const float* __restrict__ w2, const float* __restrict__ b2, int n) {
  constexpr int AST = 2 * FIN;
  constexpr int HST = 2 * FOUT;
  constexpr int NKS = FIN / 32;
  constexpr int NJT = FOUT / 16;
  constexpr int JPW = NJT / 4;
  constexpr int TPB = 40;
  __shared__ __align__(8) u8 Tl[4][16][TPB];
  u16* ho16 = (u16*)ho_;
  u8*  ho8  = (u8*)ho_;
  const int tid = threadIdx.x;
  const int w = tid >> 6, lane = tid & 63;
  const int c16 = lane & 15, kg = lane >> 4;
  for (int i = lane; i < 16 * TPB; i += 64) Tl[w][i / TPB][i % TPB] = 0;
  long aWt[JPW][NKS], aW1[NKS], aW2[JPW];
  float gbv[JPW], b2v[JPW];
  float b1v = (c16 < 10) ? b1[c16] : 0.f;
  {
    float f[8];
    #pragma unroll
    for (int ks = 0; ks < NKS; ++ks) {
      #pragma unroll
      for (int i = 0; i < 8; ++i) {
        int kk = ks * 32 + kg * 8 + i;
        f[i] = (c16 < 10) ? w1[kk * 10 + c16] : 0.f;
      }
      aW1[ks] = pk8_fp8(f);
    }
    #pragma unroll
    for (int jj = 0; jj < JPW; ++jj) {
      int colj = (w * JPW + jj) * 16 + c16;
      gbv[jj] = gb[colj]; b2v[jj] = b2[colj];
      #pragma unroll
      for (int ks = 0; ks < NKS; ++ks) {
        #pragma unroll
        for (int i = 0; i < 8; ++i)
          f[i] = gw[(ks * 32 + kg * 8 + i) * FOUT + colj];
        aWt[jj][ks] = pk8_fp8(f);
      }
      #pragma unroll
      for (int i = 0; i < 8; ++i) {
        int kk = kg * 8 + i;
        f[i] = (kk < 10) ? w2[kk * FOUT + colj] : 0.f;
      }
      aW2[jj] = pk8_fp8(f);
    }
  }
  const int ntile = n >> 4;
  for (int t = blockIdx.x; t < ntile; t += gridDim.x) {
    const int nb = t << 4;
    const u8* arow = Ain + (size_t)(nb + c16) * AST;
    long aA[NKS], aM[NKS];
    #pragma unroll
    for (int ks = 0; ks < NKS; ++ks) {
      aA[ks] = *(const long*)(arow + ks * 32 + kg * 8);
      aM[ks] = *(const long*)(arow + FIN + ks * 32 + kg * 8);
    }
    f32x4 tacc = {0.f, 0.f, 0.f, 0.f};
    #pragma unroll
    for (int ks = 0; ks < NKS; ++ks)
      tacc = __builtin_amdgcn_mfma_f32_16x16x32_fp8_fp8(aM[ks], aW1[ks], tacc, 0, 0, 0);
    #pragma unroll
    for (int r = 0; r < 4; ++r) {
      float tv = fmaxf(tacc[r] + b1v, 0.f);
      Tl[w][kg * 4 + r][c16] = (u8)pk4_fp8(tv, tv, tv, tv);
    }
    #pragma unroll
    for (int jj = 0; jj < JPW; ++jj) {
      f32x4 acc = {0.f, 0.f, 0.f, 0.f};
      #pragma unroll
      for (int ks = 0; ks < NKS; ++ks)
        acc = __builtin_amdgcn_mfma_f32_16x16x32_fp8_fp8(aA[ks], aWt[jj][ks], acc, 0, 0, 0);
      int colj = (w * JPW + jj) * 16 + c16;
      #pragma unroll
      for (int r = 0; r < 4; ++r) {
        int nd = nb + kg * 4 + r;
        float val = lrelu(acc[r] + gbv[jj]);
        if constexpr (OUT8)
          ho8[(size_t)nd * HST + colj] = (u8)pk4_fp8(val, val, val, val);
        else
          ho16[(size_t)nd * HST + colj] = f2bf(val);
      }
    }
    long at = *(const long*)&Tl[w][c16][kg * 8];
    #pragma unroll
    for (int jj = 0; jj < JPW; ++jj) {
      f32x4 acc = {0.f, 0.f, 0.f, 0.f};
      acc = __builtin_amdgcn_mfma_f32_16x16x32_fp8_fp8(at, aW2[jj], acc, 0, 0, 0);
      int colj = (w * JPW + jj) * 16 + c16;
      #pragma unroll
      for (int r = 0; r < 4; ++r) {
        int nd = nb + kg * 4 + r;
        float val = fmaxf(acc[r] + b2v[jj], 0.f);
        if constexpr (OUT8)
          ho8[(size_t)nd * HST + FOUT + colj] = (u8)pk4_fp8(val, val, val, val);
        else
          ho16[(size_t)nd * HST + FOUT + colj] = f2bf(val);
      }
    }
  }
}

// ---------------- GAT + pool (h3 fp8) ----------------

__global__ __launch_bounds__(256) void k_hjb(const u8* __restrict__ h3,
                                             const float* __restrict__ gw,
                                             const float* __restrict__ att,
                                             float* __restrict__ hj,
                                             float* __restrict__ pem, int n) {
  __shared__ float gws[256];
  __shared__ float ls[4];
  int tid = threadIdx.x;
  gws[tid] = gw[tid];
  __syncthreads();
  int w = tid >> 6, lane = tid & 63;
  float a = att[0];
  float m = -INFINITY;
  for (int node = blockIdx.x * 4 + w; node < n; node += RB_GAT * 4) {
    u32 v = *(const u32*)(h3 + (size_t)node * 256 + lane * 4);
    f32x2 p0 = __builtin_amdgcn_cvt_pk_f32_fp8((int)v, false);
    f32x2 p1 = __builtin_amdgcn_cvt_pk_f32_fp8((int)v, true);
    float acc = p0.x * gws[lane * 4] + p0.y * gws[lane * 4 + 1] +
                p1.x * gws[lane * 4 + 2] + p1.y * gws[lane * 4 + 3];
    for (int o = 32; o > 0; o >>= 1) acc += __shfl_down(acc, o);
    if (lane == 0) {
      hj[node] = acc;
      m = fmaxf(m, lrelu(a * acc));
    }
  }
  if (lane == 0) ls[w] = m;
  __syncthreads();
  if (tid == 0) pem[blockIdx.x] = fmaxf(fmaxf(ls[0], ls[1]), fmaxf(ls[2], ls[3]));
}

__global__ __launch_bounds__(256) void k_gat(const int* __restrict__ rend,
                                             const u32* __restrict__ csr_e,
                                             const float* __restrict__ hj,
                                             const float* __restrict__ att,
                                             const float* __restrict__ pem,
                                             float* __restrict__ scat,
                                             float* __restrict__ pga, int n) {
  __shared__ float ls[4];
  __shared__ float msh;
  int tid = threadIdx.x;
  float m = fmaxf(fmaxf(pem[tid], pem[tid + 256]),
                  fmaxf(pem[tid + 512], pem[tid + 768]));
  for (int o = 32; o > 0; o >>= 1) m = fmaxf(m, __shfl_down(m, o));
  int w = tid >> 6;
  if ((tid & 63) == 0) ls[w] = m;
  __syncthreads();
  if (tid == 0) msh = fmaxf(fmaxf(ls[0], ls[1]), fmaxf(ls[2], ls[3]));
  __syncthreads();
  m = msh;
  float a = att[0];
  float lsum = 0.f;
  for (int c = blockIdx.x * 256 + tid; c < n; c += RB_GAT * 256) {
    int s = (c == 0) ? 0 : rend[c - 1];
    int e = rend[c];
    float acc = 0.f;
    for (int p = s; p < e; ++p) {
      float h = hj[(int)(csr_e[p] >> 14)];
      float pex = expf(lrelu(a * h) - m);
      lsum += pex;
      acc += pex * h;
    }
    scat[c] = acc;
  }
  __syncthreads();
  for (int o = 32; o > 0; o >>= 1) lsum += __shfl_down(lsum, o);
  if ((tid & 63) == 0) ls[w] = lsum;
  __syncthreads();
  if (tid == 0) pga[blockIdx.x] = ls[0] + ls[1] + ls[2] + ls[3];
}

__global__ __launch_bounds__(256) void k_pool(
    const u8* __restrict__ h3, const float* __restrict__ scat,
    const float* __restrict__ pga,
    const float* __restrict__ lw, const float* __restrict__ lb,
    const float* __restrict__ l2w, const float* __restrict__ l2b,
    float* __restrict__ out, int ng) {
  __shared__ float ls[4];
  __shared__ float pooled[256];
  __shared__ float aw[NPGC];
  __shared__ float y[10];
  int g = blockIdx.x;
  if (g >= ng) return;
  int tid = threadIdx.x;
  float s = pga[tid] + pga[tid + 256] + pga[tid + 512] + pga[tid + 768];
  for (int o = 32; o > 0; o >>= 1) s += __shfl_down(s, o);
  int w = tid >> 6;
  if ((tid & 63) == 0) ls[w] = s;
  __syncthreads();
  float inv_sexp = 1.0f / (ls[0] + ls[1] + ls[2] + ls[3]);
  if (tid < NPGC) aw[tid] = scat[g * NPGC + tid] * inv_sexp;
  __syncthreads();
  const u8* base = h3 + (size_t)g * NPGC * 256;
  float acc = 0.f;
  #pragma unroll
  for (int u = 0; u < NPGC; ++u) {
    f32x2 p = __builtin_amdgcn_cvt_pk_f32_fp8((int)(u32)base[u * 256 + tid], false);
    acc += p.x * aw[u];
  }
  pooled[tid] = acc * (1.0f / NPGC);
  __syncthreads();
  if (tid < 10) {
    float sy = lb[tid];
    for (int f = 0; f < 256; ++f) sy += pooled[f] * lw[f * 10 + tid];
    y[tid] = sy;
  }
  __syncthreads();
  if (tid == 0) {
    float sy = l2b[0];
    #pragma unroll
    for (int k = 0; k < 10; ++k) sy += y[k] * l2w[k];
    out[g] = 1.0f / (1.0f + expf(-sy));
  }
}

extern "C" void kernel_launch(void* const* d_in, const int* in_sizes, int n_in,
                              void* d_out, int out_size, void* d_ws, size_t ws_size,
                              hipStream_t stream) {
  const float* x        = (const float*)d_in[0];
  const int*   eidx     = (const int*)d_in[1];
  const float* ew       = (const float*)d_in[2];
  const float* gcn1_w   = (const float*)d_in[3];
  const float* gcn1_b   = (const float*)d_in[4];
  const float* gcn2_w   = (const float*)d_in[5];
  const float* gcn2_b   = (const float*)d_in[6];
  const float* gcn3_w   = (const float*)d_in[7];
  const float* gcn3_b   = (const float*)d_in[8];
  const float* gin1_w1  = (const float*)d_in[9];
  const float* gin1_b1  = (const float*)d_in[10];
  const float* gin1_w2  = (const float*)d_in[11];
  const float* gin1_b2  = (const float*)d_in[12];
  const float* gin1_eps = (const float*)d_in[13];
  const float* gin2_w1  = (const float*)d_in[14];
  const float* gin2_b1  = (const float*)d_in[15];
  const float* gin2_w2  = (const float*)d_in[16];
  const float* gin2_b2  = (const float*)d_in[17];
  const float* gin2_eps = (const float*)d_in[18];
  const float* gin3_w1  = (const float*)d_in[19];
  const float* gin3_b1  = (const float*)d_in[20];
  const float* gin3_w2  = (const float*)d_in[21];
  const float* gin3_b2  = (const float*)d_in[22];
  const float* gin3_eps = (const float*)d_in[23];
  const float* gat_w    = (const float*)d_in[24];
  const float* gat_att  = (const float*)d_in[25];
  const float* lin_w    = (const float*)d_in[26];
  const float* lin_b    = (const float*)d_in[27];
  const float* lin2_w   = (const float*)d_in[28];
  const float* lin2_b   = (const float*)d_in[29];
  float* out = (float*)d_out;

  const int* row = eidx;
  const int* col = eidx + N_EDGES;

  // Workspace (~198 MB), time-multiplexed (round-16 layout, h1/h2/h3/A2/A3 fp8):
  //  R1 [N*512 B] @0:      tmp uint2[E] (N*64) -> {x0v N*16 | agg1 N*32 | h1 fp8 N*64}
  //                        -> A3 fp8 N*256
  //  R2 [N*512 B] @N*512:  h2 fp8 N*128 -> h3 fp8 N*256
  //  R3 [N*256 B] @N*1024: A2 fp8 N*128 -> {hj f32 N*4 | scat f32 N*4}
  //  tail @N*1280: rend N*4 | csr_e N*32 | histG (padded 602112 B) | btot | ebase |
  //  pcs | pem | pga
  char* B = (char*)d_ws;
  uint2*  tmp   = (uint2*)B;
  float4* x0v   = (float4*)B;
  float*  agg1  = (float*)(B + (size_t)N_NODES * 16);
  u8*     h1    = (u8*)(B + (size_t)N_NODES * 48);
  u8*     A3    = (u8*)B;
  u8*     h2    = (u8*)(B + (size_t)N_NODES * 512);
  u8*     h3    = (u8*)(B + (size_t)N_NODES * 512);
  u8*     A2    = (u8*)(B + (size_t)N_NODES * 1024);
  float*  hj    = (float*)(B + (size_t)N_NODES * 1024);
  float*  scat  = hj + N_NODES;
  int*    rend  = (int*)(B + (size_t)N_NODES * 1280);
  u32*    csr_e = (u32*)(B + (size_t)N_NODES * 1284);
  int*    histG = (int*)(B + (size_t)N_NODES * 1316);
  char*   TAIL  = B + (size_t)N_NODES * 1316 + 602112;
  int*    btot  = (int*)TAIL;
  int*    ebase = (int*)(TAIL + 4096);
  float*  pcs   = (float*)(TAIL + 8192);
  float*  pem   = (float*)(TAIL + 16384);
  float*  pga   = (float*)(TAIL + 20480);

  const int GN = (N_NODES + 255) / 256;

  // CSR build
  hipLaunchKernelGGL(k_a1, dim3(ABLK), dim3(256), 0, stream, col, histG, N_EDGES);
  hipLaunchKernelGGL(k_s1, dim3(NBKT), dim3(256), 0, stream, histG, btot);
  hipLaunchKernelGGL(k_s2, dim3(1), dim3(256), 0, stream, btot, ebase);
  hipLaunchKernelGGL(k_a2, dim3(ABLK), dim3(256), 0, stream,
                     row, col, ew, histG, ebase, tmp, N_EDGES);
  hipLaunchKernelGGL(k_b, dim3(NBKT), dim3(256), 0, stream, tmp, ebase, rend, csr_e, N_NODES);

  // normalization
  hipLaunchKernelGGL(k_cs1, dim3(RB_CS), dim3(256), 0, stream, x, pcs, N_NODES);
  hipLaunchKernelGGL(k_norm, dim3(GN), dim3(256), 0, stream, x, pcs, x0v, N_NODES);

  // layer 1: 3 -> 32|32 (h1 fp8)
  hipLaunchKernelGGL(k_gather3, dim3((N_NODES / 4 + 3) / 4), dim3(256), 0, stream,
                     x0v, rend, csr_e, gin1_eps, agg1, N_NODES);
  hipLaunchKernelGGL(k_node1, dim3(GN), dim3(256), 0, stream,
                     agg1, h1, gcn1_w, gcn1_b, gin1_w1, gin1_b1, gin1_w2, gin1_b2, N_NODES);

  // layer 2: 64 -> 64|64 (pipelined fp8 gather; fp8 MFMA; h2 fp8)
  hipLaunchKernelGGL((k_spmmb<64>), dim3((N_NODES + 31) / 32), dim3(256), 0, stream,
                     h1, A2, rend, csr_e, gin2_eps, N_NODES);
  hipLaunchKernelGGL((k_nodeM<64, 64, true>), dim3(2048), dim3(256), 0, stream,
                     A2, (void*)h2, gcn2_w, gcn2_b, gin2_w1, gin2_b1, gin2_w2, gin2_b2, N_NODES);

  // layer 3: 128 -> 128|128 (pipelined fp8 gather; fp8 MFMA; h3 fp8)
  hipLaunchKernelGGL((k_spmmb<128>), dim3((N_NODES + 15) / 16), dim3(256), 0, stream,
                     h2, A3, rend, csr_e, gin3_eps, N_NODES);
  hipLaunchKernelGGL((k_nodeM<128, 128, true>), dim3(2048), dim3(256), 0, stream,
                     A3, (void*)h3, gcn3_w, gcn3_b, gin3_w1, gin3_b1, gin3_w2, gin3_b2, N_NODES);

  // GAT (h3 fp8)
  hipLaunchKernelGGL(k_hjb, dim3(RB_GAT), dim3(256), 0, stream, h3, gat_w, gat_att, hj, pem, N_NODES);
  hipLaunchKernelGGL(k_gat, dim3(RB_GAT), dim3(256), 0, stream,
                     rend, csr_e, hj, gat_att, pem, scat, pga, N_NODES);

  // pool + readout
  hipLaunchKernelGGL(k_pool, dim3(NGRAPH), dim3(256), 0, stream,
                     h3, scat, pga, lin_w, lin_b, lin2_w, lin2_b, out, NGRAPH);
}

// Round 19
// 271.990 us; speedup vs baseline: 1.2061x; 1.0016x over previous
//
#include <hip/hip_runtime.h>
#include <hip/hip_bf16.h>
#include <math.h>

constexpr int N_NODES = 150000;
constexpr int N_EDGES = 1200000;
constexpr int NPGC    = 30;
constexpr int NGRAPH  = N_NODES / NPGC;
constexpr int RB_CS   = 256;
constexpr int RB_GAT  = 1024;
constexpr int NBKT    = (N_NODES + 255) / 256;
constexpr int ABLK    = 256;
constexpr int EPB     = (N_EDGES + ABLK - 1) / ABLK;

typedef unsigned int u32;
typedef unsigned short u16;
typedef unsigned char u8;
typedef __attribute__((ext_vector_type(4))) float f32x4;
typedef __attribute__((ext_vector_type(2))) float f32x2;

__device__ __forceinline__ float lrelu(float v) { return v > 0.f ? v : 0.2f * v; }
__device__ __forceinline__ u16 f2bf(float f) {
  u32 u = __float_as_uint(f);
  return (u16)((u + 0x7FFFu + ((u >> 16) & 1u)) >> 16);
}
__device__ __forceinline__ void unpack8f8(uint2 v, float* f) {
  f32x2 p0 = __builtin_amdgcn_cvt_pk_f32_fp8((int)v.x, false);
  f32x2 p1 = __builtin_amdgcn_cvt_pk_f32_fp8((int)v.x, true);
  f32x2 p2 = __builtin_amdgcn_cvt_pk_f32_fp8((int)v.y, false);
  f32x2 p3 = __builtin_amdgcn_cvt_pk_f32_fp8((int)v.y, true);
  f[0] = p0.x; f[1] = p0.y; f[2] = p1.x; f[3] = p1.y;
  f[4] = p2.x; f[5] = p2.y; f[6] = p3.x; f[7] = p3.y;
}
__device__ __forceinline__ u32 pk4_fp8(float a, float b, float c, float d) {
  int lo = __builtin_amdgcn_cvt_pk_fp8_f32(a, b, 0, false);
  return (u32)__builtin_amdgcn_cvt_pk_fp8_f32(c, d, lo, true);
}
__device__ __forceinline__ long pk8_fp8(const float* f) {
  union { uint2 u; long l; } cv;
  cv.u.x = pk4_fp8(f[0], f[1], f[2], f[3]);
  cv.u.y = pk4_fp8(f[4], f[5], f[6], f[7]);
  return cv.l;
}
__device__ __forceinline__ void decode_e(u32 ent, int& r, float& w) {
  r = (int)(ent >> 14);
  w = (float)(ent & 16383u) * (1.0f / 16384.0f);
}

// ---------------- CSR build: binned two-pass partition ----------------

__global__ __launch_bounds__(256) void k_a1(const int* __restrict__ col,
                                            int* __restrict__ histG, int ne) {
  __shared__ int hist[NBKT];
  int blk = blockIdx.x, tid = threadIdx.x;
  for (int i = tid; i < NBKT; i += 256) hist[i] = 0;
  __syncthreads();
  int s = blk * EPB;
  int e = s + EPB; if (e > ne) e = ne;
  for (int p = s + tid; p < e; p += 256) atomicAdd(&hist[col[p] >> 8], 1);
  __syncthreads();
  for (int i = tid; i < NBKT; i += 256) histG[i * ABLK + blk] = hist[i];
}

__global__ __launch_bounds__(256) void k_s1(int* __restrict__ histG,
                                            int* __restrict__ btot) {
  __shared__ int ts[256];
  int b = blockIdx.x, tid = threadIdx.x;
  int v = histG[b * ABLK + tid];
  ts[tid] = v;
  __syncthreads();
  for (int off = 1; off < 256; off <<= 1) {
    int t = (tid >= off) ? ts[tid - off] : 0;
    __syncthreads();
    ts[tid] += t;
    __syncthreads();
  }
  histG[b * ABLK + tid] = ts[tid] - v;
  if (tid == 255) btot[b] = ts[255];
}

__global__ __launch_bounds__(256) void k_s2(const int* __restrict__ btot,
                                            int* __restrict__ ebase) {
  __shared__ int ts[256];
  int tid = threadIdx.x;
  int v[3]; int s = 0;
  #pragma unroll
  for (int k = 0; k < 3; ++k) {
    int idx = tid * 3 + k;
    v[k] = (idx < NBKT) ? btot[idx] : 0;
    s += v[k];
  }
  ts[tid] = s;
  __syncthreads();
  for (int off = 1; off < 256; off <<= 1) {
    int t = (tid >= off) ? ts[tid - off] : 0;
    __syncthreads();
    ts[tid] += t;
    __syncthreads();
  }
  int run = ts[tid] - s;
  #pragma unroll
  for (int k = 0; k < 3; ++k) {
    int idx = tid * 3 + k;
    if (idx < NBKT) ebase[idx] = run;
    run += v[k];
  }
  if (tid == 255) ebase[NBKT] = ts[255];
}

__global__ __launch_bounds__(256) void k_a2(const int* __restrict__ row,
                                            const int* __restrict__ col,
                                            const float* __restrict__ ew,
                                            const int* __restrict__ histG,
                                            const int* __restrict__ ebase,
                                            uint2* __restrict__ tmp, int ne) {
  __shared__ int scur[NBKT];
  int blk = blockIdx.x, tid = threadIdx.x;
  for (int i = tid; i < NBKT; i += 256) scur[i] = ebase[i] + histG[i * ABLK + blk];
  __syncthreads();
  int s = blk * EPB;
  int e = s + EPB; if (e > ne) e = ne;
  for (int p = s + tid; p < e; p += 256) {
    int c = col[p];
    float w = ew[p];
    u32 wq = (u32)(w * 16384.0f + 0.5f);
    if (wq > 16383u) wq = 16383u;
    u32 ent = ((u32)row[p] << 14) | wq;
    int pos = atomicAdd(&scur[c >> 8], 1);
    uint2 v; v.x = (u32)c; v.y = ent;
    tmp[pos] = v;
  }
}

__global__ __launch_bounds__(256) void k_b(const uint2* __restrict__ tmp,
                                           const int* __restrict__ ebase,
                                           int* __restrict__ rend,
                                           u32* __restrict__ csr_e, int n) {
  __shared__ int cnt[256], cur[256], ts[256];
  int b = blockIdx.x, tid = threadIdx.x;
  int s = ebase[b], e = ebase[b + 1];
  cnt[tid] = 0;
  __syncthreads();
  for (int p = s + tid; p < e; p += 256)
    atomicAdd(&cnt[(int)tmp[p].x & 255], 1);
  __syncthreads();
  int v = cnt[tid];
  ts[tid] = v;
  __syncthreads();
  for (int off = 1; off < 256; off <<= 1) {
    int t = (tid >= off) ? ts[tid - off] : 0;
    __syncthreads();
    ts[tid] += t;
    __syncthreads();
  }
  int node = (b << 8) + tid;
  if (node < n) rend[node] = s + ts[tid];
  cur[tid] = s + ts[tid] - v;
  __syncthreads();
  for (int p = s + tid; p < e; p += 256) {
    uint2 t2 = tmp[p];
    int pos = atomicAdd(&cur[(int)t2.x & 255], 1);
    csr_e[pos] = t2.y;
  }
}

// ---------------- normalization ----------------

__global__ __launch_bounds__(256) void k_cs1(const float* __restrict__ x,
                                             float* __restrict__ pb, int n) {
  __shared__ float ls[4][6];
  float s0 = 0, s1 = 0, s2 = 0;
  float m0 = -INFINITY, m1 = -INFINITY, m2 = -INFINITY;
  for (int i = blockIdx.x * 256 + threadIdx.x; i < n; i += RB_CS * 256) {
    float v0 = x[3 * i], v1 = x[3 * i + 1], v2 = x[3 * i + 2];
    s0 += v0; s1 += v1; s2 += v2;
    m0 = fmaxf(m0, v0); m1 = fmaxf(m1, v1); m2 = fmaxf(m2, v2);
  }
  for (int o = 32; o > 0; o >>= 1) {
    s0 += __shfl_down(s0, o); s1 += __shfl_down(s1, o); s2 += __shfl_down(s2, o);
    m0 = fmaxf(m0, __shfl_down(m0, o));
    m1 = fmaxf(m1, __shfl_down(m1, o));
    m2 = fmaxf(m2, __shfl_down(m2, o));
  }
  int w = threadIdx.x >> 6;
  if ((threadIdx.x & 63) == 0) {
    ls[w][0] = s0; ls[w][1] = s1; ls[w][2] = s2;
    ls[w][3] = m0; ls[w][4] = m1; ls[w][5] = m2;
  }
  __syncthreads();
  if (threadIdx.x == 0) {
    float* o = pb + blockIdx.x * 8;
    o[0] = ls[0][0] + ls[1][0] + ls[2][0] + ls[3][0];
    o[1] = ls[0][1] + ls[1][1] + ls[2][1] + ls[3][1];
    o[2] = ls[0][2] + ls[1][2] + ls[2][2] + ls[3][2];
    o[3] = fmaxf(fmaxf(ls[0][3], ls[1][3]), fmaxf(ls[2][3], ls[3][3]));
    o[4] = fmaxf(fmaxf(ls[0][4], ls[1][4]), fmaxf(ls[2][4], ls[3][4]));
    o[5] = fmaxf(fmaxf(ls[0][5], ls[1][5]), fmaxf(ls[2][5], ls[3][5]));
  }
}

__global__ __launch_bounds__(256) void k_norm(const float* __restrict__ x,
                                              const float* __restrict__ pcs,
                                              float4* __restrict__ x0v, int n) {
  __shared__ float ls[4][6];
  __shared__ float rs[6];
  int tid = threadIdx.x;
  const float* p = pcs + tid * 8;
  float s0 = p[0], s1 = p[1], s2 = p[2], m0 = p[3], m1 = p[4], m2 = p[5];
  for (int o = 32; o > 0; o >>= 1) {
    s0 += __shfl_down(s0, o); s1 += __shfl_down(s1, o); s2 += __shfl_down(s2, o);
    m0 = fmaxf(m0, __shfl_down(m0, o));
    m1 = fmaxf(m1, __shfl_down(m1, o));
    m2 = fmaxf(m2, __shfl_down(m2, o));
  }
  int w = tid >> 6;
  if ((tid & 63) == 0) {
    ls[w][0] = s0; ls[w][1] = s1; ls[w][2] = s2;
    ls[w][3] = m0; ls[w][4] = m1; ls[w][5] = m2;
  }
  __syncthreads();
  if (tid == 0) {
    float inv_n = 1.0f / (float)N_NODES;
    #pragma unroll
    for (int c = 0; c < 3; ++c) {
      float mean = (ls[0][c] + ls[1][c] + ls[2][c] + ls[3][c]) * inv_n;
      float mx = fmaxf(fmaxf(ls[0][3 + c], ls[1][3 + c]), fmaxf(ls[2][3 + c], ls[3][3 + c]));
      rs[c] = mean;
      rs[3 + c] = 1.0f / (mx - mean);
    }
  }
  __syncthreads();
  int node = blockIdx.x * 256 + tid;
  if (node < n) {
    float vx = x[3 * node], vy = x[3 * node + 1], vz = x[3 * node + 2];
    float4 o;
    o.x = (vx - rs[0]) * rs[3];
    o.y = (vy - rs[1]) * rs[4];
    o.z = (vz - rs[2]) * rs[5];
    o.w = 0.f;
    x0v[node] = o;
  }
}

// ---------------- layer 1 ----------------

__global__ __launch_bounds__(256) void k_gather3(
    const float4* __restrict__ x0v, const int* __restrict__ rend,
    const u32* __restrict__ csr_e, const float* __restrict__ epsp,
    float* __restrict__ agg1, int n) {
  int wv = (blockIdx.x * 256 + threadIdx.x) >> 6;
  int lane = threadIdx.x & 63;
  int sub = lane >> 4, sl = lane & 15;
  int node = wv * 4 + sub;
  if (node >= n) return;
  int s = (node == 0) ? 0 : rend[node - 1];
  int e = rend[node];
  float a0 = 0, a1 = 0, a2 = 0, b0 = 0, b1 = 0, b2 = 0;
  for (int p = s + sl; p < e; p += 16) {
    int r; float w;
    decode_e(csr_e[p], r, w);
    float4 v = x0v[r];
    a0 += v.x * w; a1 += v.y * w; a2 += v.z * w;
    b0 += v.x; b1 += v.y; b2 += v.z;
  }
  #pragma unroll
  for (int o = 1; o < 16; o <<= 1) {
    a0 += __shfl_xor(a0, o); a1 += __shfl_xor(a1, o); a2 += __shfl_xor(a2, o);
    b0 += __shfl_xor(b0, o); b1 += __shfl_xor(b1, o); b2 += __shfl_xor(b2, o);
  }
  if (sl == 0) {
    float eps1 = 1.0f + epsp[0];
    float4 hv = x0v[node];
    float4* ap = (float4*)(agg1 + (size_t)node * 8);
    float4 A; A.x = a0; A.y = a1; A.z = a2; A.w = 0.f;
    float4 M; M.x = eps1 * hv.x + b0; M.y = eps1 * hv.y + b1; M.z = eps1 * hv.z + b2; M.w = 0.f;
    ap[0] = A; ap[1] = M;
  }
}

__global__ __launch_bounds__(256) void k_node1(
    const float* __restrict__ agg1, u8* __restrict__ h1,
    const float* __restrict__ gw, const float* __restrict__ gb,
    const float* __restrict__ w1, const float* __restrict__ b1,
    const float* __restrict__ w2, const float* __restrict__ b2, int n) {
  __shared__ float Ws[96], W1s[30], W2s[320], GBs[32], B1s[10], B2s[32];
  int tid = threadIdx.x;
  if (tid < 96) Ws[tid] = gw[tid];
  if (tid < 30) W1s[tid] = w1[tid];
  for (int i = tid; i < 320; i += 256) W2s[i] = w2[i];
  if (tid < 32) { GBs[tid] = gb[tid]; B2s[tid] = b2[tid]; }
  if (tid < 10) B1s[tid] = b1[tid];
  __syncthreads();
  int nd = blockIdx.x * 256 + tid;
  if (nd >= n) return;
  const float* a = agg1 + (size_t)nd * 8;
  float a0 = a[0], a1 = a[1], a2 = a[2], m0 = a[4], m1 = a[5], m2 = a[6];
  float t[10];
  #pragma unroll
  for (int h = 0; h < 10; ++h)
    t[h] = fmaxf(B1s[h] + m0 * W1s[h] + m1 * W1s[10 + h] + m2 * W1s[20 + h], 0.f);
  float vout[64];
  #pragma unroll
  for (int j = 0; j < 32; ++j)
    vout[j] = lrelu(GBs[j] + a0 * Ws[j] + a1 * Ws[32 + j] + a2 * Ws[64 + j]);
  #pragma unroll
  for (int j = 0; j < 32; ++j) {
    float s = B2s[j];
    #pragma unroll
    for (int h = 0; h < 10; ++h) s += t[h] * W2s[h * 32 + j];
    vout[32 + j] = fmaxf(s, 0.f);
  }
  u32 f8_[16];
  #pragma unroll
  for (int q = 0; q < 16; ++q)
    f8_[q] = pk4_fp8(vout[4 * q], vout[4 * q + 1], vout[4 * q + 2], vout[4 * q + 3]);
  uint4* dst = (uint4*)(h1 + (size_t)nd * 64);
  #pragma unroll
  for (int q = 0; q < 4; ++q) {
    uint4 v; v.x = f8_[q * 4]; v.y = f8_[q * 4 + 1]; v.z = f8_[q * 4 + 2]; v.w = f8_[q * 4 + 3];
    dst[q] = v;
  }
}

// ---------------- fp8 SpMM: node-group per wave, 4-deep software-pipelined gather ----------------

template <int FIN>
__global__ __launch_bounds__(256) void k_spmmb(
    const u8* __restrict__ hp, u8* __restrict__ Aout,
    const int* __restrict__ rend, const u32* __restrict__ csr_e,
    const float* __restrict__ epsp, int n) {
  constexpr int LPR = FIN / 8;
  constexpr int GPN = 64 / LPR;
  int wv = (blockIdx.x * 256 + threadIdx.x) >> 6;
  int lane = threadIdx.x & 63;
  int grp = lane / LPR;
  int fl = lane & (LPR - 1);
  int node = wv * GPN + grp;
  if (node >= n) return;
  int s = (node == 0) ? 0 : rend[node - 1];
  int e = rend[node];
  float aa[8] = {0, 0, 0, 0, 0, 0, 0, 0};
  float bb[8] = {0, 0, 0, 0, 0, 0, 0, 0};
  int p = s;
  for (; p + 4 <= e; p += 4) {
    u32 e0 = csr_e[p], e1 = csr_e[p + 1], e2 = csr_e[p + 2], e3 = csr_e[p + 3];
    int r0, r1, r2, r3; float w0, w1, w2, w3;
    decode_e(e0, r0, w0); decode_e(e1, r1, w1);
    decode_e(e2, r2, w2); decode_e(e3, r3, w3);
    uint2 v0 = *(const uint2*)(hp + (size_t)r0 * FIN + fl * 8);
    uint2 v1 = *(const uint2*)(hp + (size_t)r1 * FIN + fl * 8);
    uint2 v2 = *(const uint2*)(hp + (size_t)r2 * FIN + fl * 8);
    uint2 v3 = *(const uint2*)(hp + (size_t)r3 * FIN + fl * 8);
    float f0[8], f1[8], f2[8], f3[8];
    unpack8f8(v0, f0); unpack8f8(v1, f1); unpack8f8(v2, f2); unpack8f8(v3, f3);
    #pragma unroll
    for (int i = 0; i < 8; ++i) {
      aa[i] += f0[i] * w0 + f1[i] * w1 + f2[i] * w2 + f3[i] * w3;
      bb[i] += f0[i] + f1[i] + f2[i] + f3[i];
    }
  }
  for (; p < e; ++p) {
    int r; float w;
    decode_e(csr_e[p], r, w);
    uint2 v = *(const uint2*)(hp + (size_t)r * FIN + fl * 8);
    float f[8]; unpack8f8(v, f);
    #pragma unroll
    for (int i = 0; i < 8; ++i) { aa[i] += f[i] * w; bb[i] += f[i]; }
  }
  float eps1 = 1.0f + epsp[0];
  uint2 hv = *(const uint2*)(hp + (size_t)node * FIN + fl * 8);
  float hm[8]; unpack8f8(hv, hm);
  float m[8];
  #pragma unroll
  for (int i = 0; i < 8; ++i) m[i] = eps1 * hm[i] + bb[i];
  uint2 pa, pm;
  pa.x = pk4_fp8(aa[0], aa[1], aa[2], aa[3]);
  pa.y = pk4_fp8(aa[4], aa[5], aa[6], aa[7]);
  pm.x = pk4_fp8(m[0], m[1], m[2], m[3]);
  pm.y = pk4_fp8(m[4], m[5], m[6], m[7]);
  *(uint2*)(Aout + (size_t)node * (2 * FIN) + fl * 8) = pa;
  *(uint2*)(Aout + (size_t)node * (2 * FIN) + FIN + fl * 8) = pm;
}

// ---------------- fp8 MFMA node update: register weights, 2-tile pipelined ----------------

#define NODEM_LOAD(nb_, aA_, aM_)                                              \
  {                                                                            \
    const u8* arow = Ain + (size_t)((nb_) + c16) * AST;                        \
    _Pragma("unroll")                                                          \
    for (int ks = 0; ks < NKS; ++ks) {                                         \
      aA_[ks] = *(const long*)(arow + ks * 32 + kg * 8);                       \
      aM_[ks] = *(const long*)(arow + FIN + ks * 32 + kg * 8);                 \
    }                                                                          \
  }

#define NODEM_COMPUTE(nb_, aA_, aM_)                                           \
  {                                                                            \
    f32x4 tacc = {0.f, 0.f, 0.f, 0.f};                                         \
    _Pragma("unroll")                                                          \
    for (int ks = 0; ks < NKS; ++ks)                                           \
      tacc = __builtin_amdgcn_mfma_f32_16x16x32_fp8_fp8(aM_[ks], aW1[ks], tacc, 0, 0, 0); \
    _Pragma("unroll")                                                          \
    for (int r = 0; r < 4; ++r) {                                              \
      float tv = fmaxf(tacc[r] + b1v, 0.f);                                    \
      Tl[w][kg * 4 + r][c16] = (u8)pk4_fp8(tv, tv, tv, tv);                    \
    }                                                                          \
    _Pragma("unroll")                                                          \
    for (int jj = 0; jj < JPW; ++jj) {                                         \
      f32x4 acc = {0.f, 0.f, 0.f, 0.f};                                        \
      _Pragma("unroll")                                                        \
      for (int ks = 0; ks < NKS; ++ks)                                         \
        acc = __builtin_amdgcn_mfma_f32_16x16x32_fp8_fp8(aA_[ks], aWt[jj][ks], acc, 0, 0, 0); \
      int colj = (w * JPW + jj) * 16 + c16;                                    \
      _Pragma("unroll")                                                        \
      for (int r = 0; r < 4; ++r) {                                            \
        int nd = (nb_) + kg * 4 + r;                                           \
        float val = lrelu(acc[r] + gbv[jj]);                                   \
        ho8[(size_t)nd * HST + colj] = (u8)pk4_fp8(val, val, val, val);        \
      }                                                                        \
    }                                                                          \
    long at = *(const long*)&Tl[w][c16][kg * 8];                               \
    _Pragma("unroll")                                                          \
    for (int jj = 0; jj < JPW; ++jj) {                                         \
      f32x4 acc = {0.f, 0.f, 0.f, 0.f};                                        \
      acc = __builtin_amdgcn_mfma_f32_16x16x32_fp8_fp8(at, aW2[jj], acc, 0, 0, 0); \
      int colj = (w * JPW + jj) * 16 + c16;                                    \
      _Pragma("unroll")                                                        \
      for (int r = 0; r < 4; ++r) {                                            \
        int nd = (nb_) + kg * 4 + r;                                           \
        float val = fmaxf(acc[r] + b2v[jj], 0.f);                              \
        ho8[(size_t)nd * HST + FOUT + colj] = (u8)pk4_fp8(val, val, val, val); \
      }                                                                        \
    }                                                                          \
  }

template <int FIN, int FOUT>
__global__ __launch_bounds__(256) void k_nodeM(
    const u8* __restrict__ Ain, u8* __restrict__ ho8,
    const float* __restrict__ gw, const float* __restrict__ gb,
    const float* __restrict__ w1, const float* __restrict__ b1,
    const float* __restrict__ w2, const float* __restrict__ b2, int n) {
  constexpr int AST = 2 * FIN;
  constexpr int HST = 2 * FOUT;
  constexpr int NKS = FIN / 32;
  constexpr int NJT = FOUT / 16;
  constexpr int JPW = NJT / 4;
  constexpr int TPB = 40;
  __shared__ __align__(8) u8 Tl[4][16][TPB];
  const int tid = threadIdx.x;
  const int w = tid >> 6, lane = tid & 63;
  const int c16 = lane & 15, kg = lane >> 4;
  for (int i = lane; i < 16 * TPB; i += 64) Tl[w][i / TPB][i % TPB] = 0;
  long aWt[JPW][NKS], aW1[NKS], aW2[JPW];
  float gbv[JPW], b2v[JPW];
  float b1v = (c16 < 10) ? b1[c16] : 0.f;
  {
    float f[8];
    #pragma unroll
    for (int ks = 0; ks < NKS; ++ks) {
      #pragma unroll
      for (int i = 0; i < 8; ++i) {
        int kk = ks * 32 + kg * 8 + i;
        f[i] = (c16 < 10) ? w1[kk * 10 + c16] : 0.f;
      }
      aW1[ks] = pk8_fp8(f);
    }
    #pragma unroll
    for (int jj = 0; jj < JPW; ++jj) {
      int colj = (w * JPW + jj) * 16 + c16;
      gbv[jj] = gb[colj]; b2v[jj] = b2[colj];
      #pragma unroll
      for (int ks = 0; ks < NKS; ++ks) {
        #pragma unroll
        for (int i = 0; i < 8; ++i)
          f[i] = gw[(ks * 32 + kg * 8 + i) * FOUT + colj];
        aWt[jj][ks] = pk8_fp8(f);
      }
      #pragma unroll
      for (int i = 0; i < 8; ++i) {
        int kk = kg * 8 + i;
        f[i] = (kk < 10) ? w2[kk * FOUT + colj] : 0.f;
      }
      aW2[jj] = pk8_fp8(f);
    }
  }
  const int ntile = n >> 4;
  // 2-tile pipelined grid-stride loop: both tiles' A-frag loads issued together
  for (int t0 = blockIdx.x; t0 < ntile; t0 += 2 * gridDim.x) {
    const int t1 = t0 + gridDim.x;
    const int nb0 = t0 << 4;
    long aA0[NKS], aM0[NKS], aA1[NKS], aM1[NKS];
    NODEM_LOAD(nb0, aA0, aM0);
    if (t1 < ntile) {
      const int nb1 = t1 << 4;
      NODEM_LOAD(nb1, aA1, aM1);
      NODEM_COMPUTE(nb0, aA0, aM0);
      NODEM_COMPUTE(nb1, aA1, aM1);
    } else {
      NODEM_COMPUTE(nb0, aA0, aM0);
    }
  }
}

// ---------------- GAT + pool (h3 fp8) ----------------

__global__ __launch_bounds__(256) void k_hjb(const u8* __restrict__ h3,
                                             const float* __restrict__ gw,
                                             const float* __restrict__ att,
                                             float* __restrict__ hj,
                                             float* __restrict__ pem, int n) {
  __shared__ float gws[256];
  __shared__ float ls[4];
  int tid = threadIdx.x;
  gws[tid] = gw[tid];
  __syncthreads();
  int w = tid >> 6, lane = tid & 63;
  float a = att[0];
  float m = -INFINITY;
  for (int node = blockIdx.x * 4 + w; node < n; node += RB_GAT * 4) {
    u32 v = *(const u32*)(h3 + (size_t)node * 256 + lane * 4);
    f32x2 p0 = __builtin_amdgcn_cvt_pk_f32_fp8((int)v, false);
    f32x2 p1 = __builtin_amdgcn_cvt_pk_f32_fp8((int)v, true);
    float acc = p0.x * gws[lane * 4] + p0.y * gws[lane * 4 + 1] +
                p1.x * gws[lane * 4 + 2] + p1.y * gws[lane * 4 + 3];
    for (int o = 32; o > 0; o >>= 1) acc += __shfl_down(acc, o);
    if (lane == 0) {
      hj[node] = acc;
      m = fmaxf(m, lrelu(a * acc));
    }
  }
  if (lane == 0) ls[w] = m;
  __syncthreads();
  if (tid == 0) pem[blockIdx.x] = fmaxf(fmaxf(ls[0], ls[1]), fmaxf(ls[2], ls[3]));
}

__global__ __launch_bounds__(256) void k_gat(const int* __restrict__ rend,
                                             const u32* __restrict__ csr_e,
                                             const float* __restrict__ hj,
                                             const float* __restrict__ att,
                                             const float* __restrict__ pem,
                                             float* __restrict__ scat,
                                             float* __restrict__ pga, int n) {
  __shared__ float ls[4];
  __shared__ float msh;
  int tid = threadIdx.x;
  float m = fmaxf(fmaxf(pem[tid], pem[tid + 256]),
                  fmaxf(pem[tid + 512], pem[tid + 768]));
  for (int o = 32; o > 0; o >>= 1) m = fmaxf(m, __shfl_down(m, o));
  int w = tid >> 6;
  if ((tid & 63) == 0) ls[w] = m;
  __syncthreads();
  if (tid == 0) msh = fmaxf(fmaxf(ls[0], ls[1]), fmaxf(ls[2], ls[3]));
  __syncthreads();
  m = msh;
  float a = att[0];
  float lsum = 0.f;
  for (int c = blockIdx.x * 256 + tid; c < n; c += RB_GAT * 256) {
    int s = (c == 0) ? 0 : rend[c - 1];
    int e = rend[c];
    float acc = 0.f;
    int p = s;
    // 4-deep pipelined gather (independent hj loads in flight)
    for (; p + 4 <= e; p += 4) {
      u32 e0 = csr_e[p], e1 = csr_e[p + 1], e2 = csr_e[p + 2], e3 = csr_e[p + 3];
      float h0 = hj[(int)(e0 >> 14)];
      float h1 = hj[(int)(e1 >> 14)];
      float h2 = hj[(int)(e2 >> 14)];
      float h3v = hj[(int)(e3 >> 14)];
      float p0 = expf(lrelu(a * h0) - m);
      float p1 = expf(lrelu(a * h1) - m);
      float p2 = expf(lrelu(a * h2) - m);
      float p3 = expf(lrelu(a * h3v) - m);
      lsum += (p0 + p1) + (p2 + p3);
      acc += p0 * h0 + p1 * h1 + p2 * h2 + p3 * h3v;
    }
    for (; p < e; ++p) {
      float h = hj[(int)(csr_e[p] >> 14)];
      float pex = expf(lrelu(a * h) - m);
      lsum += pex;
      acc += pex * h;
    }
    scat[c] = acc;
  }
  __syncthreads();
  for (int o = 32; o > 0; o >>= 1) lsum += __shfl_down(lsum, o);
  if ((tid & 63) == 0) ls[w] = lsum;
  __syncthreads();
  if (tid == 0) pga[blockIdx.x] = ls[0] + ls[1] + ls[2] + ls[3];
}

__global__ __launch_bounds__(256) void k_pool(
    const u8* __restrict__ h3, const float* __restrict__ scat,
    const float* __restrict__ pga,
    const float* __restrict__ lw, const float* __restrict__ lb,
    const float* __restrict__ l2w, const float* __restrict__ l2b,
    float* __restrict__ out, int ng) {
  __shared__ float ls[4];
  __shared__ float pooled[256];
  __shared__ float aw[NPGC];
  __shared__ float y[10];
  int g = blockIdx.x;
  if (g >= ng) return;
  int tid = threadIdx.x;
  float s = pga[tid] + pga[tid + 256] + pga[tid + 512] + pga[tid + 768];
  for (int o = 32; o > 0; o >>= 1) s += __shfl_down(s, o);
  int w = tid >> 6;
  if ((tid & 63) == 0) ls[w] = s;
  __syncthreads();
  float inv_sexp = 1.0f / (ls[0] + ls[1] + ls[2] + ls[3]);
  if (tid < NPGC) aw[tid] = scat[g * NPGC + tid] * inv_sexp;
  __syncthreads();
  const u8* base = h3 + (size_t)g * NPGC * 256;
  float acc = 0.f;
  #pragma unroll
  for (int u = 0; u < NPGC; ++u) {
    f32x2 p = __builtin_amdgcn_cvt_pk_f32_fp8((int)(u32)base[u * 256 + tid], false);
    acc += p.x * aw[u];
  }
  pooled[tid] = acc * (1.0f / NPGC);
  __syncthreads();
  if (tid < 10) {
    float sy = lb[tid];
    for (int f = 0; f < 256; ++f) sy += pooled[f] * lw[f * 10 + tid];
    y[tid] = sy;
  }
  __syncthreads();
  if (tid == 0) {
    float sy = l2b[0];
    #pragma unroll
    for (int k = 0; k < 10; ++k) sy += y[k] * l2w[k];
    out[g] = 1.0f / (1.0f + expf(-sy));
  }
}

extern "C" void kernel_launch(void* const* d_in, const int* in_sizes, int n_in,
                              void* d_out, int out_size, void* d_ws, size_t ws_size,
                              hipStream_t stream) {
  const float* x        = (const float*)d_in[0];
  const int*   eidx     = (const int*)d_in[1];
  const float* ew       = (const float*)d_in[2];
  const float* gcn1_w   = (const float*)d_in[3];
  const float* gcn1_b   = (const float*)d_in[4];
  const float* gcn2_w   = (const float*)d_in[5];
  const float* gcn2_b   = (const float*)d_in[6];
  const float* gcn3_w   = (const float*)d_in[7];
  const float* gcn3_b   = (const float*)d_in[8];
  const float* gin1_w1  = (const float*)d_in[9];
  const float* gin1_b1  = (const float*)d_in[10];
  const float* gin1_w2  = (const float*)d_in[11];
  const float* gin1_b2  = (const float*)d_in[12];
  const float* gin1_eps = (const float*)d_in[13];
  const float* gin2_w1  = (const float*)d_in[14];
  const float* gin2_b1  = (const float*)d_in[15];
  const float* gin2_w2  = (const float*)d_in[16];
  const float* gin2_b2  = (const float*)d_in[17];
  const float* gin2_eps = (const float*)d_in[18];
  const float* gin3_w1  = (const float*)d_in[19];
  const float* gin3_b1  = (const float*)d_in[20];
  const float* gin3_w2  = (const float*)d_in[21];
  const float* gin3_b2  = (const float*)d_in[22];
  const float* gin3_eps = (const float*)d_in[23];
  const float* gat_w    = (const float*)d_in[24];
  const float* gat_att  = (const float*)d_in[25];
  const float* lin_w    = (const float*)d_in[26];
  const float* lin_b    = (const float*)d_in[27];
  const float* lin2_w   = (const float*)d_in[28];
  const float* lin2_b   = (const float*)d_in[29];
  float* out = (float*)d_out;

  const int* row = eidx;
  const int* col = eidx + N_EDGES;

  // Workspace (~198 MB), time-multiplexed (round-16 layout, h1/h2/h3/A2/A3 fp8):
  //  R1 [N*512 B] @0:      tmp uint2[E] (N*64) -> {x0v N*16 | agg1 N*32 | h1 fp8 N*64}
  //                        -> A3 fp8 N*256
  //  R2 [N*512 B] @N*512:  h2 fp8 N*128 -> h3 fp8 N*256
  //  R3 [N*256 B] @N*1024: A2 fp8 N*128 -> {hj f32 N*4 | scat f32 N*4}
  //  tail @N*1280: rend N*4 | csr_e N*32 | histG (padded 602112 B) | btot | ebase |
  //  pcs | pem | pga
  char* B = (char*)d_ws;
  uint2*  tmp   = (uint2*)B;
  float4* x0v   = (float4*)B;
  float*  agg1  = (float*)(B + (size_t)N_NODES * 16);
  u8*     h1    = (u8*)(B + (size_t)N_NODES * 48);
  u8*     A3    = (u8*)B;
  u8*     h2    = (u8*)(B + (size_t)N_NODES * 512);
  u8*     h3    = (u8*)(B + (size_t)N_NODES * 512);
  u8*     A2    = (u8*)(B + (size_t)N_NODES * 1024);
  float*  hj    = (float*)(B + (size_t)N_NODES * 1024);
  float*  scat  = hj + N_NODES;
  int*    rend  = (int*)(B + (size_t)N_NODES * 1280);
  u32*    csr_e = (u32*)(B + (size_t)N_NODES * 1284);
  int*    histG = (int*)(B + (size_t)N_NODES * 1316);
  char*   TAIL  = B + (size_t)N_NODES * 1316 + 602112;
  int*    btot  = (int*)TAIL;
  int*    ebase = (int*)(TAIL + 4096);
  float*  pcs   = (float*)(TAIL + 8192);
  float*  pem   = (float*)(TAIL + 16384);
  float*  pga   = (float*)(TAIL + 20480);

  const int GN = (N_NODES + 255) / 256;

  // CSR build
  hipLaunchKernelGGL(k_a1, dim3(ABLK), dim3(256), 0, stream, col, histG, N_EDGES);
  hipLaunchKernelGGL(k_s1, dim3(NBKT), dim3(256), 0, stream, histG, btot);
  hipLaunchKernelGGL(k_s2, dim3(1), dim3(256), 0, stream, btot, ebase);
  hipLaunchKernelGGL(k_a2, dim3(ABLK), dim3(256), 0, stream,
                     row, col, ew, histG, ebase, tmp, N_EDGES);
  hipLaunchKernelGGL(k_b, dim3(NBKT), dim3(256), 0, stream, tmp, ebase, rend, csr_e, N_NODES);

  // normalization
  hipLaunchKernelGGL(k_cs1, dim3(RB_CS), dim3(256), 0, stream, x, pcs, N_NODES);
  hipLaunchKernelGGL(k_norm, dim3(GN), dim3(256), 0, stream, x, pcs, x0v, N_NODES);

  // layer 1: 3 -> 32|32 (h1 fp8)
  hipLaunchKernelGGL(k_gather3, dim3((N_NODES / 4 + 3) / 4), dim3(256), 0, stream,
                     x0v, rend, csr_e, gin1_eps, agg1, N_NODES);
  hipLaunchKernelGGL(k_node1, dim3(GN), dim3(256), 0, stream,
                     agg1, h1, gcn1_w, gcn1_b, gin1_w1, gin1_b1, gin1_w2, gin1_b2, N_NODES);

  // layer 2: 64 -> 64|64 (pipelined fp8 gather; 2-tile pipelined fp8 MFMA; h2 fp8)
  hipLaunchKernelGGL((k_spmmb<64>), dim3((N_NODES + 31) / 32), dim3(256), 0, stream,
                     h1, A2, rend, csr_e, gin2_eps, N_NODES);
  hipLaunchKernelGGL((k_nodeM<64, 64>), dim3(2048), dim3(256), 0, stream,
                     A2, h2, gcn2_w, gcn2_b, gin2_w1, gin2_b1, gin2_w2, gin2_b2, N_NODES);

  // layer 3: 128 -> 128|128 (pipelined fp8 gather; 2-tile pipelined fp8 MFMA; h3 fp8)
  hipLaunchKernelGGL((k_spmmb<128>), dim3((N_NODES + 15) / 16), dim3(256), 0, stream,
                     h2, A3, rend, csr_e, gin3_eps, N_NODES);
  hipLaunchKernelGGL((k_nodeM<128, 128>), dim3(2048), dim3(256), 0, stream,
                     A3, h3, gcn3_w, gcn3_b, gin3_w1, gin3_b1, gin3_w2, gin3_b2, N_NODES);

  // GAT (h3 fp8)
  hipLaunchKernelGGL(k_hjb, dim3(RB_GAT), dim3(256), 0, stream, h3, gat_w, gat_att, hj, pem, N_NODES);
  hipLaunchKernelGGL(k_gat, dim3(RB_GAT), dim3(256), 0, stream,
                     rend, csr_e, hj, gat_att, pem, scat, pga, N_NODES);

  // pool + readout
  hipLaunchKernelGGL(k_pool, dim3(NGRAPH), dim3(256), 0, stream,
                     h3, scat, pga, lin_w, lin_b, lin2_w, lin2_b, out, NGRAPH);
}

// Round 20
// 270.110 us; speedup vs baseline: 1.2145x; 1.0070x over previous
//
#include <hip/hip_runtime.h>
#include <hip/hip_bf16.h>
#include <math.h>

constexpr int N_NODES = 150000;
constexpr int N_EDGES = 1200000;
constexpr int NPGC    = 30;
constexpr int NGRAPH  = N_NODES / NPGC;
constexpr int RB_CS   = 256;
constexpr int RB_GAT  = 1024;
constexpr int NBKT    = (N_NODES + 255) / 256;
constexpr int ABLK    = 256;
constexpr int EPB     = (N_EDGES + ABLK - 1) / ABLK;

typedef unsigned int u32;
typedef unsigned short u16;
typedef unsigned char u8;
typedef __attribute__((ext_vector_type(4))) float f32x4;
typedef __attribute__((ext_vector_type(2))) float f32x2;

__device__ __forceinline__ float lrelu(float v) { return v > 0.f ? v : 0.2f * v; }
__device__ __forceinline__ u16 f2bf(float f) {
  u32 u = __float_as_uint(f);
  return (u16)((u + 0x7FFFu + ((u >> 16) & 1u)) >> 16);
}
__device__ __forceinline__ void unpack8f8(uint2 v, float* f) {
  f32x2 p0 = __builtin_amdgcn_cvt_pk_f32_fp8((int)v.x, false);
  f32x2 p1 = __builtin_amdgcn_cvt_pk_f32_fp8((int)v.x, true);
  f32x2 p2 = __builtin_amdgcn_cvt_pk_f32_fp8((int)v.y, false);
  f32x2 p3 = __builtin_amdgcn_cvt_pk_f32_fp8((int)v.y, true);
  f[0] = p0.x; f[1] = p0.y; f[2] = p1.x; f[3] = p1.y;
  f[4] = p2.x; f[5] = p2.y; f[6] = p3.x; f[7] = p3.y;
}
__device__ __forceinline__ u32 pk4_fp8(float a, float b, float c, float d) {
  int lo = __builtin_amdgcn_cvt_pk_fp8_f32(a, b, 0, false);
  return (u32)__builtin_amdgcn_cvt_pk_fp8_f32(c, d, lo, true);
}
__device__ __forceinline__ long pk8_fp8(const float* f) {
  union { uint2 u; long l; } cv;
  cv.u.x = pk4_fp8(f[0], f[1], f[2], f[3]);
  cv.u.y = pk4_fp8(f[4], f[5], f[6], f[7]);
  return cv.l;
}
__device__ __forceinline__ void decode_e(u32 ent, int& r, float& w) {
  r = (int)(ent >> 14);
  w = (float)(ent & 16383u) * (1.0f / 16384.0f);
}

// ---------------- CSR build: binned two-pass partition ----------------

__global__ __launch_bounds__(256) void k_a1(const int* __restrict__ col,
                                            int* __restrict__ histG, int ne) {
  __shared__ int hist[NBKT];
  int blk = blockIdx.x, tid = threadIdx.x;
  for (int i = tid; i < NBKT; i += 256) hist[i] = 0;
  __syncthreads();
  int s = blk * EPB;
  int e = s + EPB; if (e > ne) e = ne;
  for (int p = s + tid; p < e; p += 256) atomicAdd(&hist[col[p] >> 8], 1);
  __syncthreads();
  for (int i = tid; i < NBKT; i += 256) histG[i * ABLK + blk] = hist[i];
}

__global__ __launch_bounds__(256) void k_s1(int* __restrict__ histG,
                                            int* __restrict__ btot) {
  __shared__ int ts[256];
  int b = blockIdx.x, tid = threadIdx.x;
  int v = histG[b * ABLK + tid];
  ts[tid] = v;
  __syncthreads();
  for (int off = 1; off < 256; off <<= 1) {
    int t = (tid >= off) ? ts[tid - off] : 0;
    __syncthreads();
    ts[tid] += t;
    __syncthreads();
  }
  histG[b * ABLK + tid] = ts[tid] - v;
  if (tid == 255) btot[b] = ts[255];
}

__global__ __launch_bounds__(256) void k_s2(const int* __restrict__ btot,
                                            int* __restrict__ ebase) {
  __shared__ int ts[256];
  int tid = threadIdx.x;
  int v[3]; int s = 0;
  #pragma unroll
  for (int k = 0; k < 3; ++k) {
    int idx = tid * 3 + k;
    v[k] = (idx < NBKT) ? btot[idx] : 0;
    s += v[k];
  }
  ts[tid] = s;
  __syncthreads();
  for (int off = 1; off < 256; off <<= 1) {
    int t = (tid >= off) ? ts[tid - off] : 0;
    __syncthreads();
    ts[tid] += t;
    __syncthreads();
  }
  int run = ts[tid] - s;
  #pragma unroll
  for (int k = 0; k < 3; ++k) {
    int idx = tid * 3 + k;
    if (idx < NBKT) ebase[idx] = run;
    run += v[k];
  }
  if (tid == 255) ebase[NBKT] = ts[255];
}

__global__ __launch_bounds__(256) void k_a2(const int* __restrict__ row,
                                            const int* __restrict__ col,
                                            const float* __restrict__ ew,
                                            const int* __restrict__ histG,
                                            const int* __restrict__ ebase,
                                            uint2* __restrict__ tmp, int ne) {
  __shared__ int scur[NBKT];
  int blk = blockIdx.x, tid = threadIdx.x;
  for (int i = tid; i < NBKT; i += 256) scur[i] = ebase[i] + histG[i * ABLK + blk];
  __syncthreads();
  int s = blk * EPB;
  int e = s + EPB; if (e > ne) e = ne;
  for (int p = s + tid; p < e; p += 256) {
    int c = col[p];
    float w = ew[p];
    u32 wq = (u32)(w * 16384.0f + 0.5f);
    if (wq > 16383u) wq = 16383u;
    u32 ent = ((u32)row[p] << 14) | wq;
    int pos = atomicAdd(&scur[c >> 8], 1);
    uint2 v; v.x = (u32)c; v.y = ent;
    tmp[pos] = v;
  }
}

__global__ __launch_bounds__(256) void k_b(const uint2* __restrict__ tmp,
                                           const int* __restrict__ ebase,
                                           int* __restrict__ rend,
                                           u32* __restrict__ csr_e, int n) {
  __shared__ int cnt[256], cur[256], ts[256];
  int b = blockIdx.x, tid = threadIdx.x;
  int s = ebase[b], e = ebase[b + 1];
  cnt[tid] = 0;
  __syncthreads();
  for (int p = s + tid; p < e; p += 256)
    atomicAdd(&cnt[(int)tmp[p].x & 255], 1);
  __syncthreads();
  int v = cnt[tid];
  ts[tid] = v;
  __syncthreads();
  for (int off = 1; off < 256; off <<= 1) {
    int t = (tid >= off) ? ts[tid - off] : 0;
    __syncthreads();
    ts[tid] += t;
    __syncthreads();
  }
  int node = (b << 8) + tid;
  if (node < n) rend[node] = s + ts[tid];
  cur[tid] = s + ts[tid] - v;
  __syncthreads();
  for (int p = s + tid; p < e; p += 256) {
    uint2 t2 = tmp[p];
    int pos = atomicAdd(&cur[(int)t2.x & 255], 1);
    csr_e[pos] = t2.y;
  }
}

// ---------------- normalization ----------------

__global__ __launch_bounds__(256) void k_cs1(const float* __restrict__ x,
                                             float* __restrict__ pb, int n) {
  __shared__ float ls[4][6];
  float s0 = 0, s1 = 0, s2 = 0;
  float m0 = -INFINITY, m1 = -INFINITY, m2 = -INFINITY;
  for (int i = blockIdx.x * 256 + threadIdx.x; i < n; i += RB_CS * 256) {
    float v0 = x[3 * i], v1 = x[3 * i + 1], v2 = x[3 * i + 2];
    s0 += v0; s1 += v1; s2 += v2;
    m0 = fmaxf(m0, v0); m1 = fmaxf(m1, v1); m2 = fmaxf(m2, v2);
  }
  for (int o = 32; o > 0; o >>= 1) {
    s0 += __shfl_down(s0, o); s1 += __shfl_down(s1, o); s2 += __shfl_down(s2, o);
    m0 = fmaxf(m0, __shfl_down(m0, o));
    m1 = fmaxf(m1, __shfl_down(m1, o));
    m2 = fmaxf(m2, __shfl_down(m2, o));
  }
  int w = threadIdx.x >> 6;
  if ((threadIdx.x & 63) == 0) {
    ls[w][0] = s0; ls[w][1] = s1; ls[w][2] = s2;
    ls[w][3] = m0; ls[w][4] = m1; ls[w][5] = m2;
  }
  __syncthreads();
  if (threadIdx.x == 0) {
    float* o = pb + blockIdx.x * 8;
    o[0] = ls[0][0] + ls[1][0] + ls[2][0] + ls[3][0];
    o[1] = ls[0][1] + ls[1][1] + ls[2][1] + ls[3][1];
    o[2] = ls[0][2] + ls[1][2] + ls[2][2] + ls[3][2];
    o[3] = fmaxf(fmaxf(ls[0][3], ls[1][3]), fmaxf(ls[2][3], ls[3][3]));
    o[4] = fmaxf(fmaxf(ls[0][4], ls[1][4]), fmaxf(ls[2][4], ls[3][4]));
    o[5] = fmaxf(fmaxf(ls[0][5], ls[1][5]), fmaxf(ls[2][5], ls[3][5]));
  }
}

__global__ __launch_bounds__(256) void k_norm(const float* __restrict__ x,
                                              const float* __restrict__ pcs,
                                              float4* __restrict__ x0v, int n) {
  __shared__ float ls[4][6];
  __shared__ float rs[6];
  int tid = threadIdx.x;
  const float* p = pcs + tid * 8;
  float s0 = p[0], s1 = p[1], s2 = p[2], m0 = p[3], m1 = p[4], m2 = p[5];
  for (int o = 32; o > 0; o >>= 1) {
    s0 += __shfl_down(s0, o); s1 += __shfl_down(s1, o); s2 += __shfl_down(s2, o);
    m0 = fmaxf(m0, __shfl_down(m0, o));
    m1 = fmaxf(m1, __shfl_down(m1, o));
    m2 = fmaxf(m2, __shfl_down(m2, o));
  }
  int w = tid >> 6;
  if ((tid & 63) == 0) {
    ls[w][0] = s0; ls[w][1] = s1; ls[w][2] = s2;
    ls[w][3] = m0; ls[w][4] = m1; ls[w][5] = m2;
  }
  __syncthreads();
  if (tid == 0) {
    float inv_n = 1.0f / (float)N_NODES;
    #pragma unroll
    for (int c = 0; c < 3; ++c) {
      float mean = (ls[0][c] + ls[1][c] + ls[2][c] + ls[3][c]) * inv_n;
      float mx = fmaxf(fmaxf(ls[0][3 + c], ls[1][3 + c]), fmaxf(ls[2][3 + c], ls[3][3 + c]));
      rs[c] = mean;
      rs[3 + c] = 1.0f / (mx - mean);
    }
  }
  __syncthreads();
  int node = blockIdx.x * 256 + tid;
  if (node < n) {
    float vx = x[3 * node], vy = x[3 * node + 1], vz = x[3 * node + 2];
    float4 o;
    o.x = (vx - rs[0]) * rs[3];
    o.y = (vy - rs[1]) * rs[4];
    o.z = (vz - rs[2]) * rs[5];
    o.w = 0.f;
    x0v[node] = o;
  }
}

// ---------------- layer 1 ----------------

__global__ __launch_bounds__(256) void k_gather3(
    const float4* __restrict__ x0v, const int* __restrict__ rend,
    const u32* __restrict__ csr_e, const float* __restrict__ epsp,
    float* __restrict__ agg1, int n) {
  int wv = (blockIdx.x * 256 + threadIdx.x) >> 6;
  int lane = threadIdx.x & 63;
  int sub = lane >> 4, sl = lane & 15;
  int node = wv * 4 + sub;
  if (node >= n) return;
  int s = (node == 0) ? 0 : rend[node - 1];
  int e = rend[node];
  float a0 = 0, a1 = 0, a2 = 0, b0 = 0, b1 = 0, b2 = 0;
  for (int p = s + sl; p < e; p += 16) {
    int r; float w;
    decode_e(csr_e[p], r, w);
    float4 v = x0v[r];
    a0 += v.x * w; a1 += v.y * w; a2 += v.z * w;
    b0 += v.x; b1 += v.y; b2 += v.z;
  }
  #pragma unroll
  for (int o = 1; o < 16; o <<= 1) {
    a0 += __shfl_xor(a0, o); a1 += __shfl_xor(a1, o); a2 += __shfl_xor(a2, o);
    b0 += __shfl_xor(b0, o); b1 += __shfl_xor(b1, o); b2 += __shfl_xor(b2, o);
  }
  if (sl == 0) {
    float eps1 = 1.0f + epsp[0];
    float4 hv = x0v[node];
    float4* ap = (float4*)(agg1 + (size_t)node * 8);
    float4 A; A.x = a0; A.y = a1; A.z = a2; A.w = 0.f;
    float4 M; M.x = eps1 * hv.x + b0; M.y = eps1 * hv.y + b1; M.z = eps1 * hv.z + b2; M.w = 0.f;
    ap[0] = A; ap[1] = M;
  }
}

__global__ __launch_bounds__(256) void k_node1(
    const float* __restrict__ agg1, u8* __restrict__ h1,
    const float* __restrict__ gw, const float* __restrict__ gb,
    const float* __restrict__ w1, const float* __restrict__ b1,
    const float* __restrict__ w2, const float* __restrict__ b2, int n) {
  __shared__ float Ws[96], W1s[30], W2s[320], GBs[32], B1s[10], B2s[32];
  int tid = threadIdx.x;
  if (tid < 96) Ws[tid] = gw[tid];
  if (tid < 30) W1s[tid] = w1[tid];
  for (int i = tid; i < 320; i += 256) W2s[i] = w2[i];
  if (tid < 32) { GBs[tid] = gb[tid]; B2s[tid] = b2[tid]; }
  if (tid < 10) B1s[tid] = b1[tid];
  __syncthreads();
  int nd = blockIdx.x * 256 + tid;
  if (nd >= n) return;
  const float* a = agg1 + (size_t)nd * 8;
  float a0 = a[0], a1 = a[1], a2 = a[2], m0 = a[4], m1 = a[5], m2 = a[6];
  float t[10];
  #pragma unroll
  for (int h = 0; h < 10; ++h)
    t[h] = fmaxf(B1s[h] + m0 * W1s[h] + m1 * W1s[10 + h] + m2 * W1s[20 + h], 0.f);
  float vout[64];
  #pragma unroll
  for (int j = 0; j < 32; ++j)
    vout[j] = lrelu(GBs[j] + a0 * Ws[j] + a1 * Ws[32 + j] + a2 * Ws[64 + j]);
  #pragma unroll
  for (int j = 0; j < 32; ++j) {
    float s = B2s[j];
    #pragma unroll
    for (int h = 0; h < 10; ++h) s += t[h] * W2s[h * 32 + j];
    vout[32 + j] = fmaxf(s, 0.f);
  }
  u32 f8_[16];
  #pragma unroll
  for (int q = 0; q < 16; ++q)
    f8_[q] = pk4_fp8(vout[4 * q], vout[4 * q + 1], vout[4 * q + 2], vout[4 * q + 3]);
  uint4* dst = (uint4*)(h1 + (size_t)nd * 64);
  #pragma unroll
  for (int q = 0; q < 4; ++q) {
    uint4 v; v.x = f8_[q * 4]; v.y = f8_[q * 4 + 1]; v.z = f8_[q * 4 + 2]; v.w = f8_[q * 4 + 3];
    dst[q] = v;
  }
}

// ---------------- fp8 SpMM: node-group per wave, 4-deep software-pipelined gather ----------------

template <int FIN>
__global__ __launch_bounds__(256) void k_spmmb(
    const u8* __restrict__ hp, u8* __restrict__ Aout,
    const int* __restrict__ rend, const u32* __restrict__ csr_e,
    const float* __restrict__ epsp, int n) {
  constexpr int LPR = FIN / 8;
  constexpr int GPN = 64 / LPR;
  int wv = (blockIdx.x * 256 + threadIdx.x) >> 6;
  int lane = threadIdx.x & 63;
  int grp = lane / LPR;
  int fl = lane & (LPR - 1);
  int node = wv * GPN + grp;
  if (node >= n) return;
  int s = (node == 0) ? 0 : rend[node - 1];
  int e = rend[node];
  float aa[8] = {0, 0, 0, 0, 0, 0, 0, 0};
  float bb[8] = {0, 0, 0, 0, 0, 0, 0, 0};
  int p = s;
  for (; p + 4 <= e; p += 4) {
    u32 e0 = csr_e[p], e1 = csr_e[p + 1], e2 = csr_e[p + 2], e3 = csr_e[p + 3];
    int r0, r1, r2, r3; float w0, w1, w2, w3;
    decode_e(e0, r0, w0); decode_e(e1, r1, w1);
    decode_e(e2, r2, w2); decode_e(e3, r3, w3);
    uint2 v0 = *(const uint2*)(hp + (size_t)r0 * FIN + fl * 8);
    uint2 v1 = *(const uint2*)(hp + (size_t)r1 * FIN + fl * 8);
    uint2 v2 = *(const uint2*)(hp + (size_t)r2 * FIN + fl * 8);
    uint2 v3 = *(const uint2*)(hp + (size_t)r3 * FIN + fl * 8);
    float f0[8], f1[8], f2[8], f3[8];
    unpack8f8(v0, f0); unpack8f8(v1, f1); unpack8f8(v2, f2); unpack8f8(v3, f3);
    #pragma unroll
    for (int i = 0; i < 8; ++i) {
      aa[i] += f0[i] * w0 + f1[i] * w1 + f2[i] * w2 + f3[i] * w3;
      bb[i] += f0[i] + f1[i] + f2[i] + f3[i];
    }
  }
  for (; p < e; ++p) {
    int r; float w;
    decode_e(csr_e[p], r, w);
    uint2 v = *(const uint2*)(hp + (size_t)r * FIN + fl * 8);
    float f[8]; unpack8f8(v, f);
    #pragma unroll
    for (int i = 0; i < 8; ++i) { aa[i] += f[i] * w; bb[i] += f[i]; }
  }
  float eps1 = 1.0f + epsp[0];
  uint2 hv = *(const uint2*)(hp + (size_t)node * FIN + fl * 8);
  float hm[8]; unpack8f8(hv, hm);
  float m[8];
  #pragma unroll
  for (int i = 0; i < 8; ++i) m[i] = eps1 * hm[i] + bb[i];
  uint2 pa, pm;
  pa.x = pk4_fp8(aa[0], aa[1], aa[2], aa[3]);
  pa.y = pk4_fp8(aa[4], aa[5], aa[6], aa[7]);
  pm.x = pk4_fp8(m[0], m[1], m[2], m[3]);
  pm.y = pk4_fp8(m[4], m[5], m[6], m[7]);
  *(uint2*)(Aout + (size_t)node * (2 * FIN) + fl * 8) = pa;
  *(uint2*)(Aout + (size_t)node * (2 * FIN) + FIN + fl * 8) = pm;
}

// ---------------- fp8 MFMA node update: register weights, barrier-free (round-18) ----------------

template <int FIN, int FOUT>
__global__ __launch_bounds__(256) void k_nodeM(
    const u8* __restrict__ Ain, u8* __restrict__ ho8,
    const float* __restrict__ gw, const float* __restrict__ gb,
    const float* __restrict__ w1, const float* __restrict__ b1,
    const float* __restrict__ w2, const float* __restrict__ b2, int n) {
  constexpr int AST = 2 * FIN;
  constexpr int HST = 2 * FOUT;
  constexpr int NKS = FIN / 32;
  constexpr int NJT = FOUT / 16;
  constexpr int JPW = NJT / 4;
  constexpr int TPB = 40;
  __shared__ __align__(8) u8 Tl[4][16][TPB];
  const int tid = threadIdx.x;
  const int w = tid >> 6, lane = tid & 63;
  const int c16 = lane & 15, kg = lane >> 4;
  for (int i = lane; i < 16 * TPB; i += 64) Tl[w][i / TPB][i % TPB] = 0;
  long aWt[JPW][NKS], aW1[NKS], aW2[JPW];
  float gbv[JPW], b2v[JPW];
  float b1v = (c16 < 10) ? b1[c16] : 0.f;
  {
    float f[8];
    #pragma unroll
    for (int ks = 0; ks < NKS; ++ks) {
      #pragma unroll
      for (int i = 0; i < 8; ++i) {
        int kk = ks * 32 + kg * 8 + i;
        f[i] = (c16 < 10) ? w1[kk * 10 + c16] : 0.f;
      }
      aW1[ks] = pk8_fp8(f);
    }
    #pragma unroll
    for (int jj = 0; jj < JPW; ++jj) {
      int colj = (w * JPW + jj) * 16 + c16;
      gbv[jj] = gb[colj]; b2v[jj] = b2[colj];
      #pragma unroll
      for (int ks = 0; ks < NKS; ++ks) {
        #pragma unroll
        for (int i = 0; i < 8; ++i)
          f[i] = gw[(ks * 32 + kg * 8 + i) * FOUT + colj];
        aWt[jj][ks] = pk8_fp8(f);
      }
      #pragma unroll
      for (int i = 0; i < 8; ++i) {
        int kk = kg * 8 + i;
        f[i] = (kk < 10) ? w2[kk * FOUT + colj] : 0.f;
      }
      aW2[jj] = pk8_fp8(f);
    }
  }
  const int ntile = n >> 4;
  for (int t = blockIdx.x; t < ntile; t += gridDim.x) {
    const int nb = t << 4;
    const u8* arow = Ain + (size_t)(nb + c16) * AST;
    long aA[NKS], aM[NKS];
    #pragma unroll
    for (int ks = 0; ks < NKS; ++ks) {
      aA[ks] = *(const long*)(arow + ks * 32 + kg * 8);
      aM[ks] = *(const long*)(arow + FIN + ks * 32 + kg * 8);
    }
    f32x4 tacc = {0.f, 0.f, 0.f, 0.f};
    #pragma unroll
    for (int ks = 0; ks < NKS; ++ks)
      tacc = __builtin_amdgcn_mfma_f32_16x16x32_fp8_fp8(aM[ks], aW1[ks], tacc, 0, 0, 0);
    #pragma unroll
    for (int r = 0; r < 4; ++r) {
      float tv = fmaxf(tacc[r] + b1v, 0.f);
      Tl[w][kg * 4 + r][c16] = (u8)pk4_fp8(tv, tv, tv, tv);
    }
    #pragma unroll
    for (int jj = 0; jj < JPW; ++jj) {
      f32x4 acc = {0.f, 0.f, 0.f, 0.f};
      #pragma unroll
      for (int ks = 0; ks < NKS; ++ks)
        acc = __builtin_amdgcn_mfma_f32_16x16x32_fp8_fp8(aA[ks], aWt[jj][ks], acc, 0, 0, 0);
      int colj = (w * JPW + jj) * 16 + c16;
      #pragma unroll
      for (int r = 0; r < 4; ++r) {
        int nd = nb + kg * 4 + r;
        float val = lrelu(acc[r] + gbv[jj]);
        ho8[(size_t)nd * HST + colj] = (u8)pk4_fp8(val, val, val, val);
      }
    }
    long at = *(const long*)&Tl[w][c16][kg * 8];
    #pragma unroll
    for (int jj = 0; jj < JPW; ++jj) {
      f32x4 acc = {0.f, 0.f, 0.f, 0.f};
      acc = __builtin_amdgcn_mfma_f32_16x16x32_fp8_fp8(at, aW2[jj], acc, 0, 0, 0);
      int colj = (w * JPW + jj) * 16 + c16;
      #pragma unroll
      for (int r = 0; r < 4; ++r) {
        int nd = nb + kg * 4 + r;
        float val = fmaxf(acc[r] + b2v[jj], 0.f);
        ho8[(size_t)nd * HST + FOUT + colj] = (u8)pk4_fp8(val, val, val, val);
      }
    }
  }
}

// ---------------- GAT + pool (h3 fp8) ----------------

__global__ __launch_bounds__(256) void k_hjb(const u8* __restrict__ h3,
                                             const float* __restrict__ gw,
                                             const float* __restrict__ att,
                                             float* __restrict__ hj,
                                             float* __restrict__ pem, int n) {
  __shared__ float gws[256];
  __shared__ float ls[4];
  int tid = threadIdx.x;
  gws[tid] = gw[tid];
  __syncthreads();
  int w = tid >> 6, lane = tid & 63;
  float a = att[0];
  float m = -INFINITY;
  for (int node = blockIdx.x * 4 + w; node < n; node += RB_GAT * 4) {
    u32 v = *(const u32*)(h3 + (size_t)node * 256 + lane * 4);
    f32x2 p0 = __builtin_amdgcn_cvt_pk_f32_fp8((int)v, false);
    f32x2 p1 = __builtin_amdgcn_cvt_pk_f32_fp8((int)v, true);
    float acc = p0.x * gws[lane * 4] + p0.y * gws[lane * 4 + 1] +
                p1.x * gws[lane * 4 + 2] + p1.y * gws[lane * 4 + 3];
    for (int o = 32; o > 0; o >>= 1) acc += __shfl_down(acc, o);
    if (lane == 0) {
      hj[node] = acc;
      m = fmaxf(m, lrelu(a * acc));
    }
  }
  if (lane == 0) ls[w] = m;
  __syncthreads();
  if (tid == 0) pem[blockIdx.x] = fmaxf(fmaxf(ls[0], ls[1]), fmaxf(ls[2], ls[3]));
}

__global__ __launch_bounds__(256) void k_gat(const int* __restrict__ rend,
                                             const u32* __restrict__ csr_e,
                                             const float* __restrict__ hj,
                                             const float* __restrict__ att,
                                             const float* __restrict__ pem,
                                             float* __restrict__ scat,
                                             float* __restrict__ pga, int n) {
  __shared__ float ls[4];
  __shared__ float msh;
  int tid = threadIdx.x;
  float m = fmaxf(fmaxf(pem[tid], pem[tid + 256]),
                  fmaxf(pem[tid + 512], pem[tid + 768]));
  for (int o = 32; o > 0; o >>= 1) m = fmaxf(m, __shfl_down(m, o));
  int w = tid >> 6;
  if ((tid & 63) == 0) ls[w] = m;
  __syncthreads();
  if (tid == 0) msh = fmaxf(fmaxf(ls[0], ls[1]), fmaxf(ls[2], ls[3]));
  __syncthreads();
  m = msh;
  float a = att[0];
  float lsum = 0.f;
  for (int c = blockIdx.x * 256 + tid; c < n; c += RB_GAT * 256) {
    int s = (c == 0) ? 0 : rend[c - 1];
    int e = rend[c];
    float acc = 0.f;
    int p = s;
    for (; p + 4 <= e; p += 4) {
      u32 e0 = csr_e[p], e1 = csr_e[p + 1], e2 = csr_e[p + 2], e3 = csr_e[p + 3];
      float h0 = hj[(int)(e0 >> 14)];
      float h1 = hj[(int)(e1 >> 14)];
      float h2 = hj[(int)(e2 >> 14)];
      float h3v = hj[(int)(e3 >> 14)];
      float p0 = expf(lrelu(a * h0) - m);
      float p1 = expf(lrelu(a * h1) - m);
      float p2 = expf(lrelu(a * h2) - m);
      float p3 = expf(lrelu(a * h3v) - m);
      lsum += (p0 + p1) + (p2 + p3);
      acc += p0 * h0 + p1 * h1 + p2 * h2 + p3 * h3v;
    }
    for (; p < e; ++p) {
      float h = hj[(int)(csr_e[p] >> 14)];
      float pex = expf(lrelu(a * h) - m);
      lsum += pex;
      acc += pex * h;
    }
    scat[c] = acc;
  }
  __syncthreads();
  for (int o = 32; o > 0; o >>= 1) lsum += __shfl_down(lsum, o);
  if ((tid & 63) == 0) ls[w] = lsum;
  __syncthreads();
  if (tid == 0) pga[blockIdx.x] = ls[0] + ls[1] + ls[2] + ls[3];
}

__global__ __launch_bounds__(256) void k_pool(
    const u8* __restrict__ h3, const float* __restrict__ scat,
    const float* __restrict__ pga,
    const float* __restrict__ lw, const float* __restrict__ lb,
    const float* __restrict__ l2w, const float* __restrict__ l2b,
    float* __restrict__ out, int ng) {
  __shared__ float ls[4];
  __shared__ float pooled[256];
  __shared__ float aw[NPGC];
  __shared__ float y[10];
  int g = blockIdx.x;
  if (g >= ng) return;
  int tid = threadIdx.x;
  float s = pga[tid] + pga[tid + 256] + pga[tid + 512] + pga[tid + 768];
  for (int o = 32; o > 0; o >>= 1) s += __shfl_down(s, o);
  int w = tid >> 6;
  if ((tid & 63) == 0) ls[w] = s;
  __syncthreads();
  float inv_sexp = 1.0f / (ls[0] + ls[1] + ls[2] + ls[3]);
  if (tid < NPGC) aw[tid] = scat[g * NPGC + tid] * inv_sexp;
  __syncthreads();
  const u8* base = h3 + (size_t)g * NPGC * 256;
  float acc = 0.f;
  #pragma unroll
  for (int u = 0; u < NPGC; ++u) {
    f32x2 p = __builtin_amdgcn_cvt_pk_f32_fp8((int)(u32)base[u * 256 + tid], false);
    acc += p.x * aw[u];
  }
  pooled[tid] = acc * (1.0f / NPGC);
  __syncthreads();
  if (tid < 10) {
    float sy = lb[tid];
    for (int f = 0; f < 256; ++f) sy += pooled[f] * lw[f * 10 + tid];
    y[tid] = sy;
  }
  __syncthreads();
  if (tid == 0) {
    float sy = l2b[0];
    #pragma unroll
    for (int k = 0; k < 10; ++k) sy += y[k] * l2w[k];
    out[g] = 1.0f / (1.0f + expf(-sy));
  }
}

extern "C" void kernel_launch(void* const* d_in, const int* in_sizes, int n_in,
                              void* d_out, int out_size, void* d_ws, size_t ws_size,
                              hipStream_t stream) {
  const float* x        = (const float*)d_in[0];
  const int*   eidx     = (const int*)d_in[1];
  const float* ew       = (const float*)d_in[2];
  const float* gcn1_w   = (const float*)d_in[3];
  const float* gcn1_b   = (const float*)d_in[4];
  const float* gcn2_w   = (const float*)d_in[5];
  const float* gcn2_b   = (const float*)d_in[6];
  const float* gcn3_w   = (const float*)d_in[7];
  const float* gcn3_b   = (const float*)d_in[8];
  const float* gin1_w1  = (const float*)d_in[9];
  const float* gin1_b1  = (const float*)d_in[10];
  const float* gin1_w2  = (const float*)d_in[11];
  const float* gin1_b2  = (const float*)d_in[12];
  const float* gin1_eps = (const float*)d_in[13];
  const float* gin2_w1  = (const float*)d_in[14];
  const float* gin2_b1  = (const float*)d_in[15];
  const float* gin2_w2  = (const float*)d_in[16];
  const float* gin2_b2  = (const float*)d_in[17];
  const float* gin2_eps = (const float*)d_in[18];
  const float* gin3_w1  = (const float*)d_in[19];
  const float* gin3_b1  = (const float*)d_in[20];
  const float* gin3_w2  = (const float*)d_in[21];
  const float* gin3_b2  = (const float*)d_in[22];
  const float* gin3_eps = (const float*)d_in[23];
  const float* gat_w    = (const float*)d_in[24];
  const float* gat_att  = (const float*)d_in[25];
  const float* lin_w    = (const float*)d_in[26];
  const float* lin_b    = (const float*)d_in[27];
  const float* lin2_w   = (const float*)d_in[28];
  const float* lin2_b   = (const float*)d_in[29];
  float* out = (float*)d_out;

  const int* row = eidx;
  const int* col = eidx + N_EDGES;

  // Workspace (~198 MB), time-multiplexed (round-16 layout, h1/h2/h3/A2/A3 fp8):
  //  R1 [N*512 B] @0:      tmp uint2[E] (N*64) -> {x0v N*16 | agg1 N*32 | h1 fp8 N*64}
  //                        -> A3 fp8 N*256
  //  R2 [N*512 B] @N*512:  h2 fp8 N*128 -> h3 fp8 N*256
  //  R3 [N*256 B] @N*1024: A2 fp8 N*128 -> {hj f32 N*4 | scat f32 N*4}
  //  tail @N*1280: rend N*4 | csr_e N*32 | histG (padded 602112 B) | btot | ebase |
  //  pcs | pem | pga
  char* B = (char*)d_ws;
  uint2*  tmp   = (uint2*)B;
  float4* x0v   = (float4*)B;
  float*  agg1  = (float*)(B + (size_t)N_NODES * 16);
  u8*     h1    = (u8*)(B + (size_t)N_NODES * 48);
  u8*     A3    = (u8*)B;
  u8*     h2    = (u8*)(B + (size_t)N_NODES * 512);
  u8*     h3    = (u8*)(B + (size_t)N_NODES * 512);
  u8*     A2    = (u8*)(B + (size_t)N_NODES * 1024);
  float*  hj    = (float*)(B + (size_t)N_NODES * 1024);
  float*  scat  = hj + N_NODES;
  int*    rend  = (int*)(B + (size_t)N_NODES * 1280);
  u32*    csr_e = (u32*)(B + (size_t)N_NODES * 1284);
  int*    histG = (int*)(B + (size_t)N_NODES * 1316);
  char*   TAIL  = B + (size_t)N_NODES * 1316 + 602112;
  int*    btot  = (int*)TAIL;
  int*    ebase = (int*)(TAIL + 4096);
  float*  pcs   = (float*)(TAIL + 8192);
  float*  pem   = (float*)(TAIL + 16384);
  float*  pga   = (float*)(TAIL + 20480);

  const int GN = (N_NODES + 255) / 256;

  // CSR build
  hipLaunchKernelGGL(k_a1, dim3(ABLK), dim3(256), 0, stream, col, histG, N_EDGES);
  hipLaunchKernelGGL(k_s1, dim3(NBKT), dim3(256), 0, stream, histG, btot);
  hipLaunchKernelGGL(k_s2, dim3(1), dim3(256), 0, stream, btot, ebase);
  hipLaunchKernelGGL(k_a2, dim3(ABLK), dim3(256), 0, stream,
                     row, col, ew, histG, ebase, tmp, N_EDGES);
  hipLaunchKernelGGL(k_b, dim3(NBKT), dim3(256), 0, stream, tmp, ebase, rend, csr_e, N_NODES);

  // normalization
  hipLaunchKernelGGL(k_cs1, dim3(RB_CS), dim3(256), 0, stream, x, pcs, N_NODES);
  hipLaunchKernelGGL(k_norm, dim3(GN), dim3(256), 0, stream, x, pcs, x0v, N_NODES);

  // layer 1: 3 -> 32|32 (h1 fp8)
  hipLaunchKernelGGL(k_gather3, dim3((N_NODES / 4 + 3) / 4), dim3(256), 0, stream,
                     x0v, rend, csr_e, gin1_eps, agg1, N_NODES);
  hipLaunchKernelGGL(k_node1, dim3(GN), dim3(256), 0, stream,
                     agg1, h1, gcn1_w, gcn1_b, gin1_w1, gin1_b1, gin1_w2, gin1_b2, N_NODES);

  // layer 2: 64 -> 64|64 (pipelined fp8 gather; fp8 MFMA; h2 fp8)
  hipLaunchKernelGGL((k_spmmb<64>), dim3((N_NODES + 31) / 32), dim3(256), 0, stream,
                     h1, A2, rend, csr_e, gin2_eps, N_NODES);
  hipLaunchKernelGGL((k_nodeM<64, 64>), dim3(2048), dim3(256), 0, stream,
                     A2, h2, gcn2_w, gcn2_b, gin2_w1, gin2_b1, gin2_w2, gin2_b2, N_NODES);

  // layer 3: 128 -> 128|128 (pipelined fp8 gather; fp8 MFMA; h3 fp8)
  hipLaunchKernelGGL((k_spmmb<128>), dim3((N_NODES + 15) / 16), dim3(256), 0, stream,
                     h2, A3, rend, csr_e, gin3_eps, N_NODES);
  hipLaunchKernelGGL((k_nodeM<128, 128>), dim3(2048), dim3(256), 0, stream,
                     A3, h3, gcn3_w, gcn3_b, gin3_w1, gin3_b1, gin3_w2, gin3_b2, N_NODES);

  // GAT (h3 fp8)
  hipLaunchKernelGGL(k_hjb, dim3(RB_GAT), dim3(256), 0, stream, h3, gat_w, gat_att, hj, pem, N_NODES);
  hipLaunchKernelGGL(k_gat, dim3(RB_GAT), dim3(256), 0, stream,
                     rend, csr_e, hj, gat_att, pem, scat, pga, N_NODES);

  // pool + readout
  hipLaunchKernelGGL(k_pool, dim3(NGRAPH), dim3(256), 0, stream,
                     h3, scat, pga, lin_w, lin_b, lin2_w, lin2_b, out, NGRAPH);
}